// Round 11
// baseline (1103.214 us; speedup 1.0000x reference)
//
#include <hip/hip_runtime.h>
#include <hip/hip_bf16.h>

// ---------------------------------------------------------------------------
// Round 11: split-KV fattn (2 blocks share the kv range; no-max softmax makes
// partials plain sums -> un-normalized bf16 O + fp32 l, tiny combine kernel).
// Doubles TLP and halves each block's serial tile chain. Rest as R10.
// ---------------------------------------------------------------------------

constexpr int BN = 4, TN = 2048, FD = 1024, CP = 200, SN = TN + CP;  // 2248
constexpr int HN = 8, DH = 128, DF = 128, MR = BN * SN;              // 8992
constexpr int SF = 3 * FD;                                           // 3072
constexpr int NT = (SN + 63) / 64;                                   // 36 tiles
constexpr int SPLIT = 2, NTH = NT / SPLIT;                           // 18 each
constexpr float C2 = 0.12751744f;  // (1/sqrt(128)) * log2(e)

typedef __attribute__((ext_vector_type(8))) short short8;
typedef __attribute__((ext_vector_type(4))) float f32x4;
typedef __attribute__((ext_vector_type(16))) float f32x16;

__device__ __forceinline__ ushort f2b(float f) {
  union { float f; uint u; } v{f};
  return (ushort)((v.u + 0x7fffu + ((v.u >> 16) & 1u)) >> 16);
}
__device__ __forceinline__ float b2f(ushort u) {
  union { uint u; float f; } v{(uint)u << 16};
  return v.f;
}
__device__ __forceinline__ uint cvt_pk_bf16(float a, float b) {
  uint r;
  asm("v_cvt_pk_bf16_f32 %0, %1, %2" : "=v"(r) : "v"(a), "v"(b));
  return r;
}
__device__ __forceinline__ float exp2_fast(float x) {
  float r;
  asm("v_exp_f32 %0, %1" : "=v"(r) : "v"(x));
  return r;
}
__device__ __forceinline__ void gld16(const void* g, void* l) {
  __builtin_amdgcn_global_load_lds(
      (const __attribute__((address_space(1))) void*)g,
      (__attribute__((address_space(3))) void*)l, 16, 0, 0);
}

// ---------------- build src bf16 (row/block) -------------------------------
__global__ __launch_bounds__(256) void k_build(const float* __restrict__ x,
                                               const float* __restrict__ proto,
                                               ushort* __restrict__ srcb) {
  const int row = blockIdx.x;  // 0..MR-1
  const int b = row / SN, s = row % SN;
  const int f = threadIdx.x * 4;
  const size_t o = (size_t)row * FD + f;
  float4 v;
  if (s < TN) {
    v = *(const float4*)(x + ((size_t)b * TN + s) * FD + f);
  } else {
    const int c = s - TN;
    v.x = proto[(size_t)(f + 0) * CP + c];
    v.y = proto[(size_t)(f + 1) * CP + c];
    v.z = proto[(size_t)(f + 2) * CP + c];
    v.w = proto[(size_t)(f + 3) * CP + c];
  }
  ushort4 u{f2b(v.x), f2b(v.y), f2b(v.z), f2b(v.w)};
  *(ushort4*)(srcb + o) = u;
}

// ---------------- flat fp32 -> bf16 (vec4) ---------------------------------
__global__ __launch_bounds__(256) void k_cvt(const float* __restrict__ in,
                                             ushort* __restrict__ out, int n) {
  const int n4 = n >> 2;
  for (int i = blockIdx.x * 256 + threadIdx.x; i < n4; i += gridDim.x * 256) {
    const float4 v = *(const float4*)(in + (size_t)i * 4);
    ushort4 u{f2b(v.x), f2b(v.y), f2b(v.z), f2b(v.w)};
    *(ushort4*)(out + (size_t)i * 4) = u;
  }
}

// ---------------- in_w (L,3F,F) fp32 -> Q/K parts to wInQK, V to wQKV ------
__global__ __launch_bounds__(256) void k_cvt_inw(const float* __restrict__ in,
                                                 ushort* __restrict__ wInQK,
                                                 ushort* __restrict__ wQKV) {
  constexpr size_t FF = (size_t)FD * FD;
  const int n4 = (int)(6 * FF / 4);
  for (int i = blockIdx.x * 256 + threadIdx.x; i < n4; i += gridDim.x * 256) {
    const size_t idx = (size_t)i * 4;
    const float4 v = *(const float4*)(in + idx);
    ushort4 u{f2b(v.x), f2b(v.y), f2b(v.z), f2b(v.w)};
    const int l = (int)(idx / (3 * FF));
    const size_t r = idx % (3 * FF);
    ushort* dst = (r >= 2 * FF) ? (wQKV + l * 3 * FF + r)
                                : (wInQK + l * 2 * FF + r);
    *(ushort4*)dst = u;
  }
}

// ---------------- transpose-convert FxF fp32 -> bf16, z = qk*2+l -----------
__global__ __launch_bounds__(256) void k_cvtT(const float* __restrict__ wq,
                                              const float* __restrict__ wk,
                                              ushort* __restrict__ wT) {
  const int z = blockIdx.z;  // qk*2 + l
  const int qk = z >> 1, l = z & 1;
  const float* W = (qk ? wk : wq) + (size_t)l * FD * FD;
  ushort* WT = wT + (size_t)z * FD * FD;
  __shared__ float t[32][33];
  const int tx = threadIdx.x & 31, ty = threadIdx.x >> 5;
  const int x0 = blockIdx.x * 32, y0 = blockIdx.y * 32;
#pragma unroll
  for (int dy = 0; dy < 4; ++dy)
    t[ty + dy * 8][tx] = W[(size_t)(y0 + ty + dy * 8) * FD + x0 + tx];
  __syncthreads();
#pragma unroll
  for (int dy = 0; dy < 4; ++dy)
    WT[(size_t)(x0 + ty + dy * 8) * FD + y0 + tx] = f2b(t[tx][ty + dy * 8]);
}

// ---------------- per-(b,h) transpose V (from packed QKV) ------------------
__global__ __launch_bounds__(256) void k_vT(const ushort* __restrict__ V,
                                            ushort* __restrict__ Vt) {
  __shared__ ushort t[32][34];
  const int tx = threadIdx.x & 31, ty = threadIdx.x >> 5;
  const int s0 = blockIdx.x * 32, d0 = blockIdx.y * 32, bh = blockIdx.z;
  const int b = bh >> 3, h = bh & 7;
#pragma unroll
  for (int dy = 0; dy < 4; ++dy) {
    const int s = min(s0 + ty + dy * 8, SN - 1);
    t[ty + dy * 8][tx] = V[((size_t)b * SN + s) * SF + h * DH + d0 + tx];
  }
  __syncthreads();
#pragma unroll
  for (int dy = 0; dy < 4; ++dy) {
    const int s = s0 + tx;
    if (s < SN)
      Vt[((size_t)bh * DH + d0 + ty + dy * 8) * SN + s] = t[tx][ty + dy * 8];
  }
}

// ---------------- conv weight repack: cw[o][tau*F+i] = W[o][i][tau] --------
__global__ __launch_bounds__(256) void k_convw(const float* __restrict__ W,
                                               ushort* __restrict__ out) {
  const int n = FD * FD * 3;
  for (int idx = blockIdx.x * 256 + threadIdx.x; idx < n;
       idx += gridDim.x * 256) {
    const int o = idx / (FD * 3);
    const int rem = idx % (FD * 3);
    const int tau = rem >> 10, i = rem & 1023;
    out[idx] = f2b(W[(size_t)o * (FD * 3) + i * 3 + tau]);
  }
}

// ---------------- zero-padded bf16 src for conv (row/block) ----------------
__global__ __launch_bounds__(256) void k_pad(const ushort* __restrict__ sb,
                                             ushort* __restrict__ pad) {
  const int r = blockIdx.x, b = blockIdx.y;  // r in [0, TN+2)
  const int f = threadIdx.x * 4;
  ushort4 v{0, 0, 0, 0};
  if (r >= 1 && r <= TN)
    v = *(const ushort4*)(sb + ((size_t)b * SN + (r - 1)) * FD + f);
  *(ushort4*)(pad + ((size_t)b * (TN + 2) + r) * FD + f) = v;
}

// ---------------- effective bias (z<2) + V-bias copy (z==2) ----------------
__global__ __launch_bounds__(256) void k_beff(const float* __restrict__ in_w,
                                              const float* __restrict__ bq,
                                              const float* __restrict__ bk,
                                              const float* __restrict__ in_b,
                                              float* __restrict__ out) {
  const int n = blockIdx.x, l = blockIdx.y, qk = blockIdx.z;
  const int tid = threadIdx.x;
  if (qk == 2) {
    if (tid == 0)
      out[l * 3 * FD + 2 * FD + n] = in_b[l * 3 * FD + 2 * FD + n];
    return;
  }
  const float* Win = in_w + (size_t)(l * 3 + qk) * FD * FD;
  const float* bv = (qk ? bk : bq) + (size_t)l * FD;
  float s = 0.f;
  for (int j = tid; j < FD; j += 256) s += Win[(size_t)n * FD + j] * bv[j];
  __shared__ float red[4];
#pragma unroll
  for (int o = 32; o; o >>= 1) s += __shfl_xor(s, o);
  if ((tid & 63) == 0) red[tid >> 6] = s;
  __syncthreads();
  if (tid == 0)
    out[l * 3 * FD + qk * FD + n] =
        red[0] + red[1] + red[2] + red[3] + in_b[l * 3 * FD + qk * FD + n];
}

// ---------------- bf16 MFMA GEMM, 128x128 (m97) ----------------------------
template <bool RELU, bool BF16OUT, bool PREP4 = false>
__global__ __launch_bounds__(256) void k_mm(const ushort* __restrict__ A,
                                            const ushort* __restrict__ W,
                                            const float* __restrict__ bias,
                                            void* __restrict__ Cv,
                                            int M, int N, int K) {
  constexpr size_t FF = (size_t)FD * FD;
  if (PREP4) {
    const int z = blockIdx.z;  // l*2 + qk
    A += (size_t)z * FF;
    W += (size_t)(((z & 1) * 2) + (z >> 1)) * FF;   // qk*2 + l
    Cv = (void*)((ushort*)Cv + (size_t)((z >> 1) * 3 + (z & 1)) * FF);
  }
  __shared__ __align__(16) ushort As[128 * 32];
  __shared__ __align__(16) ushort Ws[128 * 32];
  const int tid = threadIdx.x;
  const int lane = tid & 63, wv = tid >> 6;
  const int l15 = lane & 15, g = lane >> 4;
  const int wr = wv >> 1, wc = wv & 1;
  int bx = blockIdx.x, by = blockIdx.y;
  const int nwg = gridDim.x * gridDim.y;
  if ((nwg & 7) == 0) {  // bijective XCD swizzle (T1)
    int bid = by * gridDim.x + bx;
    bid = (bid & 7) * (nwg >> 3) + (bid >> 3);
    bx = bid % gridDim.x;
    by = bid / gridDim.x;
  }
  const int m0 = by * 128, n0 = bx * 128;
  f32x4 acc[4][4];
#pragma unroll
  for (int i = 0; i < 4; ++i)
#pragma unroll
    for (int j = 0; j < 4; ++j) acc[i][j] = (f32x4){0.f, 0.f, 0.f, 0.f};

  for (int k0 = 0; k0 < K; k0 += 32) {
#pragma unroll
    for (int j = 0; j < 2; ++j) {
      const int u = j * 256 + wv * 64 + lane;
      const int r = u >> 2, c = (u & 3) * 8;
      const int gm = min(m0 + r, M - 1);
      gld16(A + (size_t)gm * K + k0 + c, As + (size_t)u * 8);
    }
#pragma unroll
    for (int j = 0; j < 2; ++j) {
      const int u = j * 256 + wv * 64 + lane;
      const int r = u >> 2, c = (u & 3) * 8;
      gld16(W + (size_t)(n0 + r) * K + k0 + c, Ws + (size_t)u * 8);
    }
    __syncthreads();
    short8 af[4], bfr[4];
#pragma unroll
    for (int i = 0; i < 4; ++i)
      af[i] = *(const short8*)(As + (wr * 64 + i * 16 + l15) * 32 + g * 8);
#pragma unroll
    for (int j = 0; j < 4; ++j)
      bfr[j] = *(const short8*)(Ws + (wc * 64 + j * 16 + l15) * 32 + g * 8);
    __builtin_amdgcn_s_setprio(1);
#pragma unroll
    for (int i = 0; i < 4; ++i)
#pragma unroll
      for (int j = 0; j < 4; ++j)
        acc[i][j] = __builtin_amdgcn_mfma_f32_16x16x32_bf16(af[i], bfr[j],
                                                            acc[i][j], 0, 0, 0);
    __builtin_amdgcn_s_setprio(0);
    __syncthreads();
  }
#pragma unroll
  for (int i = 0; i < 4; ++i) {
#pragma unroll
    for (int r = 0; r < 4; ++r) {
      const int row = m0 + wr * 64 + i * 16 + g * 4 + r;
      if (row >= M) continue;
#pragma unroll
      for (int j = 0; j < 4; ++j) {
        const int col = n0 + wc * 64 + j * 16 + l15;
        float v = acc[i][j][r];
        if (bias) v += bias[col];
        if (RELU) v = fmaxf(v, 0.f);
        if (BF16OUT)
          ((ushort*)Cv)[(size_t)row * N + col] = f2b(v);
        else
          ((float*)Cv)[(size_t)row * N + col] = v;
      }
    }
  }
}

// ---------------- big GEMM: 128x256, BK=64, 8 waves, dbuf + vmcnt(6) -------
template <bool CONV, bool BF16OUT>
__global__ __launch_bounds__(512, 1) void k_mmB(const ushort* __restrict__ A,
                                                const ushort* __restrict__ W,
                                                const float* __restrict__ bias,
                                                void* __restrict__ Cv,
                                                int M, int N, int K) {
  __shared__ __align__(16) ushort As[2][128 * 64];
  __shared__ __align__(16) ushort Bs[2][256 * 64];
  const int tid = threadIdx.x;
  const int lane = tid & 63, wv = tid >> 6;
  const int l15 = lane & 15, g = lane >> 4;
  const int wr = wv >> 2, wc = wv & 3;  // 2 x 4 wave grid
  int bx = blockIdx.x, by = blockIdx.y;
  const int nwg = gridDim.x * gridDim.y;
  if ((nwg & 7) == 0) {  // bijective XCD swizzle (T1)
    int bid = by * gridDim.x + bx;
    bid = (bid & 7) * (nwg >> 3) + (bid >> 3);
    bx = bid % gridDim.x;
    by = bid / gridDim.x;
  }
  const int m0 = by * 128, n0 = bx * 256;
  const int NKt = K >> 6;

  f32x4 acc[4][4];
#pragma unroll
  for (int i = 0; i < 4; ++i)
#pragma unroll
    for (int j = 0; j < 4; ++j) acc[i][j] = (f32x4){0.f, 0.f, 0.f, 0.f};

  auto stage = [&](int kt, int d) {
    const int kb = kt * 64;
#pragma unroll
    for (int j = 0; j < 2; ++j) {
      const int u = j * 512 + tid;          // 0..1023
      const int row = u >> 3, s = u & 7;    // row 0..127, 16B slot
      const int c = s ^ (row & 7);
      const ushort* ga;
      if (CONV) {
        const int rm = m0 + row;
        const int bb = rm >> 11, tt = rm & 2047;
        ga = A + (size_t)(bb * (TN + 2) + tt + (kb >> 10)) * FD + (kb & 1023) +
             c * 8;
      } else {
        ga = A + (size_t)min(m0 + row, M - 1) * K + kb + c * 8;
      }
      gld16(ga, As[d] + row * 64 + s * 8);
    }
#pragma unroll
    for (int j = 0; j < 4; ++j) {
      const int u = j * 512 + tid;          // 0..2047
      const int row = u >> 3, s = u & 7;    // row 0..255
      const int c = s ^ (row & 7);
      gld16(W + (size_t)(n0 + row) * K + kb + c * 8, Bs[d] + row * 64 + s * 8);
    }
  };

  stage(0, 0);
  for (int kt = 0; kt < NKt; ++kt) {
    const int cur = kt & 1;
    if (kt + 1 < NKt) {
      stage(kt + 1, cur ^ 1);
      asm volatile("s_waitcnt vmcnt(6)" ::: "memory");
    } else {
      asm volatile("s_waitcnt vmcnt(0)" ::: "memory");
    }
    __builtin_amdgcn_s_barrier();
    __builtin_amdgcn_sched_barrier(0);
#pragma unroll
    for (int ks = 0; ks < 2; ++ks) {
      short8 aq[4], bq[4];
#pragma unroll
      for (int mf = 0; mf < 4; ++mf) {
        const int row = wr * 64 + mf * 16 + l15;
        aq[mf] = *(const short8*)(As[cur] + row * 64 +
                                  (((ks * 4 + g) ^ (row & 7)) << 3));
      }
#pragma unroll
      for (int nf = 0; nf < 4; ++nf) {
        const int row = wc * 64 + nf * 16 + l15;
        bq[nf] = *(const short8*)(Bs[cur] + row * 64 +
                                  (((ks * 4 + g) ^ (row & 7)) << 3));
      }
      __builtin_amdgcn_s_setprio(1);
#pragma unroll
      for (int mf = 0; mf < 4; ++mf)
#pragma unroll
        for (int nf = 0; nf < 4; ++nf)
          acc[mf][nf] = __builtin_amdgcn_mfma_f32_16x16x32_bf16(
              aq[mf], bq[nf], acc[mf][nf], 0, 0, 0);
      __builtin_amdgcn_s_setprio(0);
    }
    asm volatile("s_waitcnt lgkmcnt(0)" ::: "memory");
    __builtin_amdgcn_s_barrier();
  }

#pragma unroll
  for (int mf = 0; mf < 4; ++mf) {
#pragma unroll
    for (int r = 0; r < 4; ++r) {
      const int row = m0 + wr * 64 + mf * 16 + g * 4 + r;
      if (!CONV && row >= M) continue;
#pragma unroll
      for (int nf = 0; nf < 4; ++nf) {
        const int col = n0 + wc * 64 + nf * 16 + l15;
        float v = acc[mf][nf][r];
        if (bias) v += bias[col];
        if (CONV) {
          v = fmaxf(v, 0.f);
          const int bb = row >> 11, tt = row & 2047;
          ((float*)Cv)[((size_t)(bb * FD + col)) * TN + tt] = v;
        } else if (BF16OUT) {
          ((ushort*)Cv)[(size_t)row * N + col] = f2b(v);
        } else {
          ((float*)Cv)[(size_t)row * N + col] = v;
        }
      }
    }
  }
}

// ---------------- flash attention: 32x32 MFMA, QB=64, split-KV -------------
// 2304 blocks; each handles half the kv range. Output: un-normalized bf16 O
// partial + fp32 row-sum l. bh-major XCD remap keeps K/V L2-local.
__global__ __launch_bounds__(128) void k_fattn(const ushort* __restrict__ Qg,
                                               const ushort* __restrict__ Kg,
                                               const ushort* __restrict__ Vt,
                                               ushort* __restrict__ Op,
                                               float* __restrict__ lbuf) {
  __shared__ __align__(16) ushort Ks[64 * 128];     // 16KB, 16 slots/row
  __shared__ __align__(16) ushort Vs[128 * 64];     // 16KB, 8 slots/row
  __shared__ __align__(16) ushort Ps[2][32 * 64];   // 8KB, per-wave P
  const int tid = threadIdx.x, lane = tid & 63, wv = tid >> 6;
  const int l31 = lane & 31, hh = lane >> 5;
  // XCD remap over 2304 blocks: combo c = (b*2+sp)*8 + h gets its 36 q-tiles
  // pinned to XCD c&7.
  const int flat = blockIdx.x + NT * (blockIdx.y + HN * blockIdx.z);
  const int xcd = flat & 7, slot = flat >> 3;       // slot 0..287
  const int c64 = xcd + 8 * (slot / NT);            // combo 0..63
  const int qt = slot % NT;
  const int h = c64 & 7, z2 = c64 >> 3;             // z2 = b*2+sp
  const int b = z2 >> 1, sp = z2 & 1;
  const int q0 = qt * 64;
  const size_t rowBase = (size_t)b * SN;
  const int hoff = h * DH;
  const size_t vbase = (size_t)(b * HN + h) * DH * SN;
  ushort* op = Op + (size_t)sp * MR * FD;

  // Q as B-frags: qf[ks] = Q[q0+wv*32+l31][ks*16 + hh*8 .. +8]
  short8 qf[8];
  const int qrow = min(q0 + wv * 32 + l31, SN - 1);
#pragma unroll
  for (int ks = 0; ks < 8; ++ks)
    qf[ks] = *(const short8*)(Qg + (rowBase + qrow) * SF + hoff + ks * 16 +
                              hh * 8);

  f32x16 o[4];
#pragma unroll
  for (int dn = 0; dn < 4; ++dn)
#pragma unroll
    for (int r = 0; r < 16; ++r) o[dn][r] = 0.f;
  float lacc = 0.f;
  const char* KsB = (const char*)Ks;
  const char* VsB = (const char*)Vs;
  char* PsB = (char*)&Ps[wv][0];

  for (int t = sp * NTH; t < sp * NTH + NTH; ++t) {
    const int kv0 = t * 64;
    const bool tl = (t == NT - 1);
    // stage K [64 rows][16 slots], slot s holds chunk s^(row&15)
#pragma unroll
    for (int j = 0; j < 8; ++j) {
      const int su = j * 128 + tid;
      const int row = su >> 4, s = su & 15;
      const int c16 = s ^ (row & 15);
      const int krow = tl ? min(kv0 + row, SN - 1) : kv0 + row;
      gld16(Kg + (rowBase + krow) * SF + hoff + c16 * 8, Ks + (size_t)su * 8);
    }
    // stage Vt [128 rows][8 slots], slot s holds chunk s^(row&7)
#pragma unroll
    for (int j = 0; j < 8; ++j) {
      const int su = j * 128 + tid;
      const int row = su >> 3, s = su & 7;
      const int cc = s ^ (row & 7);
      const int kvc = tl ? min(kv0 + cc * 8, SN - 8) : kv0 + cc * 8;
      gld16(Vt + vbase + (size_t)row * SN + kvc, Vs + (size_t)su * 8);
    }
    __syncthreads();

    // S^T = K · Q^T, two kv-halves interleaved (independent MFMA chains)
    f32x16 st0, st1;
#pragma unroll
    for (int r = 0; r < 16; ++r) { st0[r] = 0.f; st1[r] = 0.f; }
    __builtin_amdgcn_s_setprio(1);
#pragma unroll
    for (int ks = 0; ks < 8; ++ks) {
      const int slot = (ks * 2 + hh) ^ (l31 & 15);
      const short8 kf0 = *(const short8*)(KsB + l31 * 256 + slot * 16);
      const short8 kf1 = *(const short8*)(KsB + (32 + l31) * 256 + slot * 16);
      st0 = __builtin_amdgcn_mfma_f32_32x32x16_bf16(kf0, qf[ks], st0, 0, 0, 0);
      st1 = __builtin_amdgcn_mfma_f32_32x32x16_bf16(kf1, qf[ks], st1, 0, 0, 0);
    }
    __builtin_amdgcn_s_setprio(0);

    // softmax (no-max, exp2 direct) + pack to P, per kv-half
    auto smax = [&](const f32x16& stv, int mt) {
      float pfl[16];
      if (tl) {
#pragma unroll
        for (int r = 0; r < 16; ++r) {
          const int kvg = kv0 + mt * 32 + (r & 3) + 8 * (r >> 2) + 4 * hh;
          pfl[r] = (kvg < SN) ? exp2_fast(C2 * stv[r]) : 0.f;
        }
      } else {
#pragma unroll
        for (int r = 0; r < 16; ++r) pfl[r] = exp2_fast(C2 * stv[r]);
      }
      float ls = 0.f;
#pragma unroll
      for (int r = 0; r < 16; ++r) ls += pfl[r];
      lacc += ls;
#pragma unroll
      for (int gg = 0; gg < 4; ++gg) {
        const uint lo = cvt_pk_bf16(pfl[4 * gg + 0], pfl[4 * gg + 1]);
        const uint hi = cvt_pk_bf16(pfl[4 * gg + 2], pfl[4 * gg + 3]);
        const int slot = (mt * 4 + gg) ^ (l31 & 7);
        *(uint2*)(PsB + l31 * 128 + slot * 16 + hh * 8) = make_uint2(lo, hi);
      }
    };
    smax(st0, 0);
    smax(st1, 1);

    // PV: O += P · V  (A=P rows=q, B=V^T cols=d)
    __builtin_amdgcn_s_setprio(1);
#pragma unroll
    for (int ks = 0; ks < 4; ++ks) {
      const int pslot = ((ks << 1) | hh) ^ (l31 & 7);
      const short8 pf = *(const short8*)(PsB + l31 * 128 + pslot * 16);
#pragma unroll
      for (int dn = 0; dn < 4; ++dn) {
        const int vrow = dn * 32 + l31;
        const int vslot = ((ks << 1) | hh) ^ (vrow & 7);
        const short8 vf = *(const short8*)(VsB + vrow * 128 + vslot * 16);
        o[dn] = __builtin_amdgcn_mfma_f32_32x32x16_bf16(pf, vf, o[dn], 0, 0, 0);
      }
    }
    __builtin_amdgcn_s_setprio(0);
    __syncthreads();
  }

  // epilogue: fold lane halves of the row-sum; write l + un-normalized O
  lacc += __shfl_xor(lacc, 32);
  const int qself = q0 + wv * 32 + l31;
  if (hh == 0 && qself < SN)
    lbuf[((size_t)(sp * BN + b) * HN + h) * SN + qself] = lacc;
#pragma unroll
  for (int r = 0; r < 16; ++r) {
    const int ql = (r & 3) + 8 * (r >> 2) + 4 * hh;
    const int orow = q0 + wv * 32 + ql;
    if (orow >= SN) continue;
#pragma unroll
    for (int dn = 0; dn < 4; ++dn)
      op[(rowBase + orow) * FD + hoff + dn * 32 + l31] = f2b(o[dn][r]);
  }
}

// ---------------- combine split-KV partials: O=(O0+O1)/(l0+l1) -------------
__global__ __launch_bounds__(256) void k_comb(const ushort* __restrict__ Op,
                                              const float* __restrict__ lbuf,
                                              ushort* __restrict__ out) {
  const int row = blockIdx.x;
  const int b = row / SN, s = row % SN;
  const int c = threadIdx.x * 4;
  const int h = c >> 7;
  const size_t off = (size_t)row * FD + c;
  const float l0 = lbuf[((size_t)(0 * BN + b) * HN + h) * SN + s];
  const float l1 = lbuf[((size_t)(1 * BN + b) * HN + h) * SN + s];
  const float inv = 1.f / (l0 + l1);
  const ushort4 a = *(const ushort4*)(Op + off);
  const ushort4 d = *(const ushort4*)(Op + (size_t)MR * FD + off);
  ushort4 u{f2b((b2f(a.x) + b2f(d.x)) * inv),
            f2b((b2f(a.y) + b2f(d.y)) * inv),
            f2b((b2f(a.z) + b2f(d.z)) * inv),
            f2b((b2f(a.w) + b2f(d.w)) * inv)};
  *(ushort4*)(out + off) = u;
}

// ---------------- fused residual + LayerNorm (bf16 stream, fp32 math) ------
__global__ __launch_bounds__(256) void k_add_ln(ushort* __restrict__ sb,
                                                const ushort* __restrict__ d,
                                                const float* __restrict__ g,
                                                const float* __restrict__ be) {
  __shared__ float red[4];
  const int row = blockIdx.x;
  const int tid = threadIdx.x;
  const int c = tid * 4;
  const size_t off = (size_t)row * FD + c;
  const ushort4 sv = *(const ushort4*)(sb + off);
  const ushort4 dv = *(const ushort4*)(d + off);
  float v[4] = {b2f(sv.x) + b2f(dv.x), b2f(sv.y) + b2f(dv.y),
                b2f(sv.z) + b2f(dv.z), b2f(sv.w) + b2f(dv.w)};
  float sum = v[0] + v[1] + v[2] + v[3];
#pragma unroll
  for (int o = 32; o; o >>= 1) sum += __shfl_xor(sum, o);
  if ((tid & 63) == 0) red[tid >> 6] = sum;
  __syncthreads();
  sum = red[0] + red[1] + red[2] + red[3];
  const float mu = sum * (1.f / FD);
  float vs = 0.f;
#pragma unroll
  for (int i = 0; i < 4; ++i) {
    const float t = v[i] - mu;
    vs += t * t;
  }
  __syncthreads();
#pragma unroll
  for (int o = 32; o; o >>= 1) vs += __shfl_xor(vs, o);
  if ((tid & 63) == 0) red[tid >> 6] = vs;
  __syncthreads();
  vs = red[0] + red[1] + red[2] + red[3];
  const float rstd = rsqrtf(vs * (1.f / FD) + 1e-5f);
  const float4 gv = *(const float4*)(g + c);
  const float4 bv = *(const float4*)(be + c);
  ushort4 u{f2b((v[0] - mu) * rstd * gv.x + bv.x),
            f2b((v[1] - mu) * rstd * gv.y + bv.y),
            f2b((v[2] - mu) * rstd * gv.z + bv.z),
            f2b((v[3] - mu) * rstd * gv.w + bv.w)};
  *(ushort4*)(sb + off) = u;
}

// ---------------------------------------------------------------------------
extern "C" void kernel_launch(void* const* d_in, const int* in_sizes, int n_in,
                              void* d_out, int out_size, void* d_ws,
                              size_t ws_size, hipStream_t stream) {
  const float* x      = (const float*)d_in[0];
  const float* proto  = (const float*)d_in[1];
  const float* wq     = (const float*)d_in[2];
  const float* bq     = (const float*)d_in[3];
  const float* wk     = (const float*)d_in[4];
  const float* bk     = (const float*)d_in[5];
  const float* in_w   = (const float*)d_in[6];
  const float* in_b   = (const float*)d_in[7];
  const float* out_w  = (const float*)d_in[8];
  const float* out_b  = (const float*)d_in[9];
  const float* l1_w   = (const float*)d_in[10];
  const float* l1_b   = (const float*)d_in[11];
  const float* l2_w   = (const float*)d_in[12];
  const float* l2_b   = (const float*)d_in[13];
  const float* ln1_g  = (const float*)d_in[14];
  const float* ln1_b  = (const float*)d_in[15];
  const float* ln2_g  = (const float*)d_in[16];
  const float* ln2_b  = (const float*)d_in[17];
  const float* emb_w  = (const float*)d_in[18];
  const float* emb_b  = (const float*)d_in[19];

  char* p = (char*)d_ws;
  auto take = [&](size_t bytes) {
    char* r = p;
    p += (bytes + 255) & ~(size_t)255;
    return r;
  };
  const size_t MF = (size_t)MR * FD;
  const size_t FF = (size_t)FD * FD;
  ushort* srcb  = (ushort*)take(MF * 2);
  ushort* bQKV  = (ushort*)take((size_t)MR * SF * 2);   // 55 MB, multi-aliased
  ushort* bVt   = (ushort*)take((size_t)BN * HN * DH * SN * 2);
  ushort* bO    = (ushort*)take(MF * 2);
  ushort* bOp   = (ushort*)take((size_t)SPLIT * MF * 2);  // split partials
  float*  lbuf  = (float*)take((size_t)SPLIT * BN * HN * SN * 4);
  ushort* bFF   = (ushort*)take((size_t)MR * DF * 2);
  ushort* wQKV  = (ushort*)take((size_t)2 * 3 * FF * 2);  // packed weights
  ushort* wOut  = (ushort*)take((size_t)2 * FF * 2);
  ushort* wL1   = (ushort*)take((size_t)2 * DF * FD * 2);
  ushort* wL2   = (ushort*)take((size_t)2 * FD * DF * 2);
  float*  bqkv  = (float*)take((size_t)2 * SF * 4);
  // aliases inside bQKV (lifetimes disjoint from activation use):
  ushort* wT     = bQKV;                       // prep: 4 * F*F bf16
  ushort* wInQK  = bQKV + 4 * FF;              // prep: 4 * F*F bf16
  ushort* bOut   = bQKV;                       // post-attn / post-FFN2 bf16
  ushort* srcPad = bQKV;                       // tail: B*(TN+2)*F bf16
  ushort* convW  = bQKV + (size_t)10 * 1024 * 1024;  // tail: 3*F*F bf16

  // ---- prep (all weight-only work hoisted, consolidated) ----
  k_build<<<MR, 256, 0, stream>>>(x, proto, srcb);
  k_cvt_inw<<<2048, 256, 0, stream>>>(in_w, wInQK, wQKV);
  k_cvt<<<1024, 256, 0, stream>>>(out_w, wOut, 2 * FF);
  k_cvt<<<256, 256, 0, stream>>>(l1_w, wL1, 2 * DF * FD);
  k_cvt<<<256, 256, 0, stream>>>(l2_w, wL2, 2 * FD * DF);
  k_cvtT<<<dim3(32, 32, 4), 256, 0, stream>>>(wq, wk, wT);
  k_mm<false, true, true><<<dim3(8, 8, 4), 256, 0, stream>>>(
      wInQK, wT, nullptr, wQKV, FD, FD, FD);
  k_beff<<<dim3(FD, 2, 3), 256, 0, stream>>>(in_w, bq, bk, in_b, bqkv);

  const int MB = (MR + 127) / 128;  // 71 M-blocks for the big GEMMs

  // ---- layers ----
  for (int l = 0; l < 2; ++l) {
    k_mmB<false, true><<<dim3(SF / 256, MB), 512, 0, stream>>>(
        srcb, wQKV + (size_t)l * 3 * FF, bqkv + (size_t)l * SF, bQKV, MR, SF,
        FD);
    k_vT<<<dim3((SN + 31) / 32, DH / 32, BN * HN), 256, 0, stream>>>(
        bQKV + 2 * FD, bVt);
    k_fattn<<<dim3(NT, HN, BN * SPLIT), 128, 0, stream>>>(
        bQKV, bQKV + FD, bVt, bOp, lbuf);
    k_comb<<<MR, 256, 0, stream>>>(bOp, lbuf, bO);
    k_mmB<false, true><<<dim3(FD / 256, MB), 512, 0, stream>>>(
        bO, wOut + (size_t)l * FF, out_b + (size_t)l * FD, bOut, MR, FD, FD);
    k_add_ln<<<MR, 256, 0, stream>>>(srcb, bOut, ln1_g + (size_t)l * FD,
                                     ln1_b + (size_t)l * FD);
    k_mm<true, true><<<dim3(DF / 128, MB), 256, 0, stream>>>(
        srcb, wL1 + (size_t)l * DF * FD, l1_b + (size_t)l * DF, bFF, MR, DF,
        FD);
    k_mm<false, true><<<dim3(FD / 128, MB), 256, 0, stream>>>(
        bFF, wL2 + (size_t)l * FD * DF, l2_b + (size_t)l * FD, bOut, MR, FD,
        DF);
    k_add_ln<<<MR, 256, 0, stream>>>(srcb, bOut, ln2_g + (size_t)l * FD,
                                     ln2_b + (size_t)l * FD);
  }

  // ---- conv head ----
  k_convw<<<1024, 256, 0, stream>>>(emb_w, convW);
  k_pad<<<dim3(TN + 2, BN), 256, 0, stream>>>(srcb, srcPad);
  k_mmB<true, false><<<dim3(FD / 256, (BN * TN) / 128), 512, 0, stream>>>(
      srcPad, convW, emb_b, (float*)d_out, BN * TN, FD, 3 * FD);
}

// Round 12
// 915.119 us; speedup vs baseline: 1.2055x; 1.2055x over previous
//
#include <hip/hip_runtime.h>
#include <hip/hip_bf16.h>

// ---------------------------------------------------------------------------
// Round 12: revert to measured-best components. fattn = R6-exact (161us:
// QB=64, 4 waves, 16x16, single-buffer, no-max softmax) + bh-major XCD remap.
// All big GEMMs back on 128x128 k_mm (m97 912-TF structure; k_mmB was -58us).
// ---------------------------------------------------------------------------

constexpr int BN = 4, TN = 2048, FD = 1024, CP = 200, SN = TN + CP;  // 2248
constexpr int HN = 8, DH = 128, DF = 128, MR = BN * SN;              // 8992
constexpr int SF = 3 * FD;                                           // 3072
constexpr int NT = (SN + 63) / 64;                                   // 36 tiles
constexpr float C2 = 0.12751744f;  // (1/sqrt(128)) * log2(e)

typedef __attribute__((ext_vector_type(8))) short short8;
typedef __attribute__((ext_vector_type(4))) float f32x4;

__device__ __forceinline__ ushort f2b(float f) {
  union { float f; uint u; } v{f};
  return (ushort)((v.u + 0x7fffu + ((v.u >> 16) & 1u)) >> 16);
}
__device__ __forceinline__ float b2f(ushort u) {
  union { uint u; float f; } v{(uint)u << 16};
  return v.f;
}
__device__ __forceinline__ uint cvt_pk_bf16(float a, float b) {
  uint r;
  asm("v_cvt_pk_bf16_f32 %0, %1, %2" : "=v"(r) : "v"(a), "v"(b));
  return r;
}
__device__ __forceinline__ float exp2_fast(float x) {
  float r;
  asm("v_exp_f32 %0, %1" : "=v"(r) : "v"(x));
  return r;
}
__device__ __forceinline__ void gld16(const void* g, void* l) {
  __builtin_amdgcn_global_load_lds(
      (const __attribute__((address_space(1))) void*)g,
      (__attribute__((address_space(3))) void*)l, 16, 0, 0);
}

// ---------------- build src bf16 (row/block) -------------------------------
__global__ __launch_bounds__(256) void k_build(const float* __restrict__ x,
                                               const float* __restrict__ proto,
                                               ushort* __restrict__ srcb) {
  const int row = blockIdx.x;  // 0..MR-1
  const int b = row / SN, s = row % SN;
  const int f = threadIdx.x * 4;
  const size_t o = (size_t)row * FD + f;
  float4 v;
  if (s < TN) {
    v = *(const float4*)(x + ((size_t)b * TN + s) * FD + f);
  } else {
    const int c = s - TN;
    v.x = proto[(size_t)(f + 0) * CP + c];
    v.y = proto[(size_t)(f + 1) * CP + c];
    v.z = proto[(size_t)(f + 2) * CP + c];
    v.w = proto[(size_t)(f + 3) * CP + c];
  }
  ushort4 u{f2b(v.x), f2b(v.y), f2b(v.z), f2b(v.w)};
  *(ushort4*)(srcb + o) = u;
}

// ---------------- flat fp32 -> bf16 (vec4) ---------------------------------
__global__ __launch_bounds__(256) void k_cvt(const float* __restrict__ in,
                                             ushort* __restrict__ out, int n) {
  const int n4 = n >> 2;
  for (int i = blockIdx.x * 256 + threadIdx.x; i < n4; i += gridDim.x * 256) {
    const float4 v = *(const float4*)(in + (size_t)i * 4);
    ushort4 u{f2b(v.x), f2b(v.y), f2b(v.z), f2b(v.w)};
    *(ushort4*)(out + (size_t)i * 4) = u;
  }
}

// ---------------- in_w (L,3F,F) fp32 -> Q/K parts to wInQK, V to wQKV ------
__global__ __launch_bounds__(256) void k_cvt_inw(const float* __restrict__ in,
                                                 ushort* __restrict__ wInQK,
                                                 ushort* __restrict__ wQKV) {
  constexpr size_t FF = (size_t)FD * FD;
  const int n4 = (int)(6 * FF / 4);
  for (int i = blockIdx.x * 256 + threadIdx.x; i < n4; i += gridDim.x * 256) {
    const size_t idx = (size_t)i * 4;
    const float4 v = *(const float4*)(in + idx);
    ushort4 u{f2b(v.x), f2b(v.y), f2b(v.z), f2b(v.w)};
    const int l = (int)(idx / (3 * FF));
    const size_t r = idx % (3 * FF);
    ushort* dst = (r >= 2 * FF) ? (wQKV + l * 3 * FF + r)
                                : (wInQK + l * 2 * FF + r);
    *(ushort4*)dst = u;
  }
}

// ---------------- transpose-convert FxF fp32 -> bf16, z = qk*2+l -----------
__global__ __launch_bounds__(256) void k_cvtT(const float* __restrict__ wq,
                                              const float* __restrict__ wk,
                                              ushort* __restrict__ wT) {
  const int z = blockIdx.z;  // qk*2 + l
  const int qk = z >> 1, l = z & 1;
  const float* W = (qk ? wk : wq) + (size_t)l * FD * FD;
  ushort* WT = wT + (size_t)z * FD * FD;
  __shared__ float t[32][33];
  const int tx = threadIdx.x & 31, ty = threadIdx.x >> 5;
  const int x0 = blockIdx.x * 32, y0 = blockIdx.y * 32;
#pragma unroll
  for (int dy = 0; dy < 4; ++dy)
    t[ty + dy * 8][tx] = W[(size_t)(y0 + ty + dy * 8) * FD + x0 + tx];
  __syncthreads();
#pragma unroll
  for (int dy = 0; dy < 4; ++dy)
    WT[(size_t)(x0 + ty + dy * 8) * FD + y0 + tx] = f2b(t[tx][ty + dy * 8]);
}

// ---------------- per-(b,h) transpose V (from packed QKV) ------------------
__global__ __launch_bounds__(256) void k_vT(const ushort* __restrict__ V,
                                            ushort* __restrict__ Vt) {
  __shared__ ushort t[32][34];
  const int tx = threadIdx.x & 31, ty = threadIdx.x >> 5;
  const int s0 = blockIdx.x * 32, d0 = blockIdx.y * 32, bh = blockIdx.z;
  const int b = bh >> 3, h = bh & 7;
#pragma unroll
  for (int dy = 0; dy < 4; ++dy) {
    const int s = min(s0 + ty + dy * 8, SN - 1);
    t[ty + dy * 8][tx] = V[((size_t)b * SN + s) * SF + h * DH + d0 + tx];
  }
  __syncthreads();
#pragma unroll
  for (int dy = 0; dy < 4; ++dy) {
    const int s = s0 + tx;
    if (s < SN)
      Vt[((size_t)bh * DH + d0 + ty + dy * 8) * SN + s] = t[tx][ty + dy * 8];
  }
}

// ---------------- conv weight repack: cw[o][tau*F+i] = W[o][i][tau] --------
__global__ __launch_bounds__(256) void k_convw(const float* __restrict__ W,
                                               ushort* __restrict__ out) {
  const int n = FD * FD * 3;
  for (int idx = blockIdx.x * 256 + threadIdx.x; idx < n;
       idx += gridDim.x * 256) {
    const int o = idx / (FD * 3);
    const int rem = idx % (FD * 3);
    const int tau = rem >> 10, i = rem & 1023;
    out[idx] = f2b(W[(size_t)o * (FD * 3) + i * 3 + tau]);
  }
}

// ---------------- zero-padded bf16 src for conv (row/block) ----------------
__global__ __launch_bounds__(256) void k_pad(const ushort* __restrict__ sb,
                                             ushort* __restrict__ pad) {
  const int r = blockIdx.x, b = blockIdx.y;  // r in [0, TN+2)
  const int f = threadIdx.x * 4;
  ushort4 v{0, 0, 0, 0};
  if (r >= 1 && r <= TN)
    v = *(const ushort4*)(sb + ((size_t)b * SN + (r - 1)) * FD + f);
  *(ushort4*)(pad + ((size_t)b * (TN + 2) + r) * FD + f) = v;
}

// ---------------- effective bias (z<2) + V-bias copy (z==2) ----------------
__global__ __launch_bounds__(256) void k_beff(const float* __restrict__ in_w,
                                              const float* __restrict__ bq,
                                              const float* __restrict__ bk,
                                              const float* __restrict__ in_b,
                                              float* __restrict__ out) {
  const int n = blockIdx.x, l = blockIdx.y, qk = blockIdx.z;
  const int tid = threadIdx.x;
  if (qk == 2) {
    if (tid == 0)
      out[l * 3 * FD + 2 * FD + n] = in_b[l * 3 * FD + 2 * FD + n];
    return;
  }
  const float* Win = in_w + (size_t)(l * 3 + qk) * FD * FD;
  const float* bv = (qk ? bk : bq) + (size_t)l * FD;
  float s = 0.f;
  for (int j = tid; j < FD; j += 256) s += Win[(size_t)n * FD + j] * bv[j];
  __shared__ float red[4];
#pragma unroll
  for (int o = 32; o; o >>= 1) s += __shfl_xor(s, o);
  if ((tid & 63) == 0) red[tid >> 6] = s;
  __syncthreads();
  if (tid == 0)
    out[l * 3 * FD + qk * FD + n] =
        red[0] + red[1] + red[2] + red[3] + in_b[l * 3 * FD + qk * FD + n];
}

// ---------------- bf16 MFMA GEMM, 128x128 (m97 structure) ------------------
// PREP4: z-batched W_eff prep. CONV: padded-row A addressing (K=3*FD) and
// fp32 NCH output with relu.
template <bool RELU, bool BF16OUT, bool PREP4 = false, bool CONV = false>
__global__ __launch_bounds__(256) void k_mm(const ushort* __restrict__ A,
                                            const ushort* __restrict__ W,
                                            const float* __restrict__ bias,
                                            void* __restrict__ Cv,
                                            int M, int N, int K) {
  constexpr size_t FF = (size_t)FD * FD;
  if (PREP4) {
    const int z = blockIdx.z;  // l*2 + qk
    A += (size_t)z * FF;
    W += (size_t)(((z & 1) * 2) + (z >> 1)) * FF;   // qk*2 + l
    Cv = (void*)((ushort*)Cv + (size_t)((z >> 1) * 3 + (z & 1)) * FF);
  }
  __shared__ __align__(16) ushort As[128 * 32];
  __shared__ __align__(16) ushort Ws[128 * 32];
  const int tid = threadIdx.x;
  const int lane = tid & 63, wv = tid >> 6;
  const int l15 = lane & 15, g = lane >> 4;
  const int wr = wv >> 1, wc = wv & 1;
  int bx = blockIdx.x, by = blockIdx.y;
  const int nwg = gridDim.x * gridDim.y;
  if ((nwg & 7) == 0) {  // bijective XCD swizzle (T1)
    int bid = by * gridDim.x + bx;
    bid = (bid & 7) * (nwg >> 3) + (bid >> 3);
    bx = bid % gridDim.x;
    by = bid / gridDim.x;
  }
  const int m0 = by * 128, n0 = bx * 128;
  f32x4 acc[4][4];
#pragma unroll
  for (int i = 0; i < 4; ++i)
#pragma unroll
    for (int j = 0; j < 4; ++j) acc[i][j] = (f32x4){0.f, 0.f, 0.f, 0.f};

  for (int k0 = 0; k0 < K; k0 += 32) {
#pragma unroll
    for (int j = 0; j < 2; ++j) {
      const int u = j * 256 + wv * 64 + lane;
      const int r = u >> 2, c = (u & 3) * 8;
      const ushort* ga;
      if (CONV) {
        const int rm = m0 + r;  // M multiple of 128
        const int bb = rm >> 11, tt = rm & 2047;
        ga = A + (size_t)(bb * (TN + 2) + tt + (k0 >> 10)) * FD + (k0 & 1023) +
             c;
      } else {
        ga = A + (size_t)min(m0 + r, M - 1) * K + k0 + c;
      }
      gld16(ga, As + (size_t)u * 8);
    }
#pragma unroll
    for (int j = 0; j < 2; ++j) {
      const int u = j * 256 + wv * 64 + lane;
      const int r = u >> 2, c = (u & 3) * 8;
      gld16(W + (size_t)(n0 + r) * K + k0 + c, Ws + (size_t)u * 8);
    }
    __syncthreads();
    short8 af[4], bfr[4];
#pragma unroll
    for (int i = 0; i < 4; ++i)
      af[i] = *(const short8*)(As + (wr * 64 + i * 16 + l15) * 32 + g * 8);
#pragma unroll
    for (int j = 0; j < 4; ++j)
      bfr[j] = *(const short8*)(Ws + (wc * 64 + j * 16 + l15) * 32 + g * 8);
    __builtin_amdgcn_s_setprio(1);
#pragma unroll
    for (int i = 0; i < 4; ++i)
#pragma unroll
      for (int j = 0; j < 4; ++j)
        acc[i][j] = __builtin_amdgcn_mfma_f32_16x16x32_bf16(af[i], bfr[j],
                                                            acc[i][j], 0, 0, 0);
    __builtin_amdgcn_s_setprio(0);
    __syncthreads();
  }
#pragma unroll
  for (int i = 0; i < 4; ++i) {
#pragma unroll
    for (int r = 0; r < 4; ++r) {
      const int row = m0 + wr * 64 + i * 16 + g * 4 + r;
      if (!CONV && row >= M) continue;
#pragma unroll
      for (int j = 0; j < 4; ++j) {
        const int col = n0 + wc * 64 + j * 16 + l15;
        float v = acc[i][j][r];
        if (bias) v += bias[col];
        if (RELU || CONV) v = fmaxf(v, 0.f);
        if (CONV) {
          const int bb = row >> 11, tt = row & 2047;
          ((float*)Cv)[((size_t)(bb * FD + col)) * TN + tt] = v;
        } else if (BF16OUT) {
          ((ushort*)Cv)[(size_t)row * N + col] = f2b(v);
        } else {
          ((float*)Cv)[(size_t)row * N + col] = v;
        }
      }
    }
  }
}

// ---------------- flash attention: R6-exact + bh-major XCD remap -----------
// QB=64, 4 waves, 16x16 MFMA, single-buffer, no-max exp2 softmax, MFMA
// row-sum (ones fragment), cvt_pk P-pack, XOR-swizzled K/V/P.
__global__ __launch_bounds__(256) void k_fattn(const ushort* __restrict__ Qg,
                                               const ushort* __restrict__ Kg,
                                               const ushort* __restrict__ Vt,
                                               ushort* __restrict__ Og) {
  __shared__ __align__(16) ushort Ks[64 * 128];
  __shared__ __align__(16) ushort Vs[128 * 64];
  __shared__ __align__(16) ushort Ps[4][16 * 64];
  const int tid = threadIdx.x, lane = tid & 63, wv = tid >> 6;
  const int l15 = lane & 15, g = lane >> 4;
  // bh-major XCD remap: 1152 blocks; bh-group grp's 36 q-tiles pinned to
  // XCD grp%8 (K/V stay L2-local).  flat bijective over 8*144.
  const int flat = blockIdx.x + NT * (blockIdx.y + HN * blockIdx.z);
  const int xcd = flat & 7, slot = flat >> 3;   // slot 0..143
  const int grp = xcd + 8 * (slot / NT);        // bh 0..31
  const int qt = slot % NT;
  const int b = grp >> 3, h = grp & 7, q0 = qt * 64;
  const size_t rowBase = (size_t)b * SN;
  const int hoff = h * DH;
  const size_t vbase = (size_t)grp * DH * SN;

  short8 qf[4];
  const int qrow = min(q0 + wv * 16 + l15, SN - 1);
#pragma unroll
  for (int c = 0; c < 4; ++c)
    qf[c] = *(const short8*)(Qg + (rowBase + qrow) * SF + hoff + c * 32 + g * 8);

  short8 onesf;
#pragma unroll
  for (int i = 0; i < 8; ++i) onesf[i] = (short)0x3F80;  // bf16 1.0

  f32x4 o[8];
#pragma unroll
  for (int dt = 0; dt < 8; ++dt) o[dt] = (f32x4){0.f, 0.f, 0.f, 0.f};
  f32x4 lacc = (f32x4){0.f, 0.f, 0.f, 0.f};  // MFMA row-sum of P
  const char* KsB = (const char*)Ks;
  const char* VsB = (const char*)Vs;
  char* PsB = (char*)&Ps[wv][0];

  for (int t = 0; t < NT; ++t) {
    const int kv0 = t * 64;
    const bool tl = (t == NT - 1);
    if (tl) {
#pragma unroll
      for (int j = 0; j < 4; ++j) {
        const int su = j * 256 + tid;
        const int row = su >> 4, s = su & 15;
        const int c16 = s ^ (row & 7);
        const int krow = min(kv0 + row, SN - 1);
        gld16(Kg + (rowBase + krow) * SF + hoff + c16 * 8, Ks + (size_t)su * 8);
      }
#pragma unroll
      for (int j = 0; j < 4; ++j) {
        const int su = j * 256 + tid;
        const int row = su >> 3, s = su & 7;
        const int cc = s ^ (row & 7);
        const int kvc = min(kv0 + cc * 8, SN - 8);
        gld16(Vt + vbase + (size_t)row * SN + kvc, Vs + (size_t)su * 8);
      }
    } else {
#pragma unroll
      for (int j = 0; j < 4; ++j) {
        const int su = j * 256 + tid;
        const int row = su >> 4, s = su & 15;
        const int c16 = s ^ (row & 7);
        gld16(Kg + (rowBase + kv0 + row) * SF + hoff + c16 * 8,
              Ks + (size_t)su * 8);
      }
#pragma unroll
      for (int j = 0; j < 4; ++j) {
        const int su = j * 256 + tid;
        const int row = su >> 3, s = su & 7;
        const int cc = s ^ (row & 7);
        gld16(Vt + vbase + (size_t)row * SN + kv0 + cc * 8,
              Vs + (size_t)su * 8);
      }
    }
    __syncthreads();

    // S^T = K · Q^T
    f32x4 st[4];
    __builtin_amdgcn_s_setprio(1);
#pragma unroll
    for (int kt = 0; kt < 4; ++kt) {
      f32x4 s4 = (f32x4){0.f, 0.f, 0.f, 0.f};
      const int row = kt * 16 + l15;
#pragma unroll
      for (int c = 0; c < 4; ++c) {
        const short8 kf = *(const short8*)(
            KsB + row * 256 + (((c * 4 + g) ^ (row & 7)) << 4));
        s4 = __builtin_amdgcn_mfma_f32_16x16x32_bf16(kf, qf[c], s4, 0, 0, 0);
      }
      st[kt] = s4;
    }
    __builtin_amdgcn_s_setprio(0);

    // no-max softmax: p = 2^(C2*s); mask only on tail tile
    float pfl[16];
    if (tl) {
#pragma unroll
      for (int kt = 0; kt < 4; ++kt)
#pragma unroll
        for (int r = 0; r < 4; ++r) {
          const int kvg = kv0 + kt * 16 + g * 4 + r;
          pfl[kt * 4 + r] = (kvg < SN) ? exp2_fast(C2 * st[kt][r]) : 0.f;
        }
    } else {
#pragma unroll
      for (int i = 0; i < 16; ++i)
        pfl[i] = exp2_fast(C2 * st[i >> 2][i & 3]);
    }

    // write P: row l15, 16B slots XOR-swizzled by (l15&7)
#pragma unroll
    for (int kt = 0; kt < 4; ++kt) {
      const uint lo = cvt_pk_bf16(pfl[kt * 4 + 0], pfl[kt * 4 + 1]);
      const uint hi = cvt_pk_bf16(pfl[kt * 4 + 2], pfl[kt * 4 + 3]);
      const int slot = (kt * 2 + (g >> 1)) ^ (l15 & 7);
      *(uint2*)(PsB + l15 * 128 + slot * 16 + (g & 1) * 8) = make_uint2(lo, hi);
    }

    // PV: O += P · V ; lacc += P · 1 (row-sum via matrix pipe)
    __builtin_amdgcn_s_setprio(1);
#pragma unroll
    for (int c2 = 0; c2 < 2; ++c2) {
      const int pslot = (c2 * 4 + g) ^ (l15 & 7);
      const short8 pf = *(const short8*)(PsB + l15 * 128 + pslot * 16);
      lacc = __builtin_amdgcn_mfma_f32_16x16x32_bf16(pf, onesf, lacc, 0, 0, 0);
#pragma unroll
      for (int dt = 0; dt < 8; ++dt) {
        const int row = dt * 16 + l15;
        const short8 vf = *(const short8*)(
            VsB + row * 128 + (((c2 * 4 + g) ^ (row & 7)) << 4));
        o[dt] = __builtin_amdgcn_mfma_f32_16x16x32_bf16(pf, vf, o[dt], 0, 0, 0);
      }
    }
    __builtin_amdgcn_s_setprio(0);
    __syncthreads();
  }

  float ir[4];
#pragma unroll
  for (int r = 0; r < 4; ++r) ir[r] = 1.f / lacc[r];
#pragma unroll
  for (int r = 0; r < 4; ++r) {
    const int orow = q0 + wv * 16 + g * 4 + r;
    if (orow >= SN) continue;
#pragma unroll
    for (int dt = 0; dt < 8; ++dt)
      Og[(rowBase + orow) * FD + hoff + dt * 16 + l15] = f2b(o[dt][r] * ir[r]);
  }
}

// ---------------- fused residual + LayerNorm (bf16 stream, fp32 math) ------
__global__ __launch_bounds__(256) void k_add_ln(ushort* __restrict__ sb,
                                                const ushort* __restrict__ d,
                                                const float* __restrict__ g,
                                                const float* __restrict__ be) {
  __shared__ float red[4];
  const int row = blockIdx.x;
  const int tid = threadIdx.x;
  const int c = tid * 4;
  const size_t off = (size_t)row * FD + c;
  const ushort4 sv = *(const ushort4*)(sb + off);
  const ushort4 dv = *(const ushort4*)(d + off);
  float v[4] = {b2f(sv.x) + b2f(dv.x), b2f(sv.y) + b2f(dv.y),
                b2f(sv.z) + b2f(dv.z), b2f(sv.w) + b2f(dv.w)};
  float sum = v[0] + v[1] + v[2] + v[3];
#pragma unroll
  for (int o = 32; o; o >>= 1) sum += __shfl_xor(sum, o);
  if ((tid & 63) == 0) red[tid >> 6] = sum;
  __syncthreads();
  sum = red[0] + red[1] + red[2] + red[3];
  const float mu = sum * (1.f / FD);
  float vs = 0.f;
#pragma unroll
  for (int i = 0; i < 4; ++i) {
    const float t = v[i] - mu;
    vs += t * t;
  }
  __syncthreads();
#pragma unroll
  for (int o = 32; o; o >>= 1) vs += __shfl_xor(vs, o);
  if ((tid & 63) == 0) red[tid >> 6] = vs;
  __syncthreads();
  vs = red[0] + red[1] + red[2] + red[3];
  const float rstd = rsqrtf(vs * (1.f / FD) + 1e-5f);
  const float4 gv = *(const float4*)(g + c);
  const float4 bv = *(const float4*)(be + c);
  ushort4 u{f2b((v[0] - mu) * rstd * gv.x + bv.x),
            f2b((v[1] - mu) * rstd * gv.y + bv.y),
            f2b((v[2] - mu) * rstd * gv.z + bv.z),
            f2b((v[3] - mu) * rstd * gv.w + bv.w)};
  *(ushort4*)(sb + off) = u;
}

// ---------------------------------------------------------------------------
extern "C" void kernel_launch(void* const* d_in, const int* in_sizes, int n_in,
                              void* d_out, int out_size, void* d_ws,
                              size_t ws_size, hipStream_t stream) {
  const float* x      = (const float*)d_in[0];
  const float* proto  = (const float*)d_in[1];
  const float* wq     = (const float*)d_in[2];
  const float* bq     = (const float*)d_in[3];
  const float* wk     = (const float*)d_in[4];
  const float* bk     = (const float*)d_in[5];
  const float* in_w   = (const float*)d_in[6];
  const float* in_b   = (const float*)d_in[7];
  const float* out_w  = (const float*)d_in[8];
  const float* out_b  = (const float*)d_in[9];
  const float* l1_w   = (const float*)d_in[10];
  const float* l1_b   = (const float*)d_in[11];
  const float* l2_w   = (const float*)d_in[12];
  const float* l2_b   = (const float*)d_in[13];
  const float* ln1_g  = (const float*)d_in[14];
  const float* ln1_b  = (const float*)d_in[15];
  const float* ln2_g  = (const float*)d_in[16];
  const float* ln2_b  = (const float*)d_in[17];
  const float* emb_w  = (const float*)d_in[18];
  const float* emb_b  = (const float*)d_in[19];

  char* p = (char*)d_ws;
  auto take = [&](size_t bytes) {
    char* r = p;
    p += (bytes + 255) & ~(size_t)255;
    return r;
  };
  const size_t MF = (size_t)MR * FD;
  const size_t FF = (size_t)FD * FD;
  ushort* srcb  = (ushort*)take(MF * 2);
  ushort* bQKV  = (ushort*)take((size_t)MR * SF * 2);   // 55 MB, multi-aliased
  ushort* bVt   = (ushort*)take((size_t)BN * HN * DH * SN * 2);
  ushort* bO    = (ushort*)take(MF * 2);
  ushort* bFF   = (ushort*)take((size_t)MR * DF * 2);
  ushort* wQKV  = (ushort*)take((size_t)2 * 3 * FF * 2);  // packed weights
  ushort* wOut  = (ushort*)take((size_t)2 * FF * 2);
  ushort* wL1   = (ushort*)take((size_t)2 * DF * FD * 2);
  ushort* wL2   = (ushort*)take((size_t)2 * FD * DF * 2);
  float*  bqkv  = (float*)take((size_t)2 * SF * 4);
  // aliases inside bQKV (lifetimes disjoint from activation use):
  ushort* wT     = bQKV;                       // prep: 4 * F*F bf16
  ushort* wInQK  = bQKV + 4 * FF;              // prep: 4 * F*F bf16
  ushort* bOut   = bQKV;                       // post-attn / post-FFN2 bf16
  ushort* srcPad = bQKV;                       // tail: B*(TN+2)*F bf16
  ushort* convW  = bQKV + (size_t)10 * 1024 * 1024;  // tail: 3*F*F bf16

  // ---- prep (all weight-only work hoisted, consolidated) ----
  k_build<<<MR, 256, 0, stream>>>(x, proto, srcb);
  k_cvt_inw<<<2048, 256, 0, stream>>>(in_w, wInQK, wQKV);
  k_cvt<<<1024, 256, 0, stream>>>(out_w, wOut, 2 * FF);
  k_cvt<<<256, 256, 0, stream>>>(l1_w, wL1, 2 * DF * FD);
  k_cvt<<<256, 256, 0, stream>>>(l2_w, wL2, 2 * FD * DF);
  k_cvtT<<<dim3(32, 32, 4), 256, 0, stream>>>(wq, wk, wT);
  k_mm<false, true, true><<<dim3(8, 8, 4), 256, 0, stream>>>(
      wInQK, wT, nullptr, wQKV, FD, FD, FD);
  k_beff<<<dim3(FD, 2, 3), 256, 0, stream>>>(in_w, bq, bk, in_b, bqkv);

  const int MB = (MR + 127) / 128;  // 71 M-blocks for the big GEMMs

  // ---- layers ----
  for (int l = 0; l < 2; ++l) {
    k_mm<false, true><<<dim3(SF / 128, MB), 256, 0, stream>>>(
        srcb, wQKV + (size_t)l * 3 * FF, bqkv + (size_t)l * SF, bQKV, MR, SF,
        FD);
    k_vT<<<dim3((SN + 31) / 32, DH / 32, BN * HN), 256, 0, stream>>>(
        bQKV + 2 * FD, bVt);
    k_fattn<<<dim3(NT, HN, BN), 256, 0, stream>>>(bQKV, bQKV + FD, bVt, bO);
    k_mm<false, true><<<dim3(FD / 128, MB), 256, 0, stream>>>(
        bO, wOut + (size_t)l * FF, out_b + (size_t)l * FD, bOut, MR, FD, FD);
    k_add_ln<<<MR, 256, 0, stream>>>(srcb, bOut, ln1_g + (size_t)l * FD,
                                     ln1_b + (size_t)l * FD);
    k_mm<true, true><<<dim3(DF / 128, MB), 256, 0, stream>>>(
        srcb, wL1 + (size_t)l * DF * FD, l1_b + (size_t)l * DF, bFF, MR, DF,
        FD);
    k_mm<false, true><<<dim3(FD / 128, MB), 256, 0, stream>>>(
        bFF, wL2 + (size_t)l * FD * DF, l2_b + (size_t)l * FD, bOut, MR, FD,
        DF);
    k_add_ln<<<MR, 256, 0, stream>>>(srcb, bOut, ln2_g + (size_t)l * FD,
                                     ln2_b + (size_t)l * FD);
  }

  // ---- conv head ----
  k_convw<<<1024, 256, 0, stream>>>(emb_w, convW);
  k_pad<<<dim3(TN + 2, BN), 256, 0, stream>>>(srcb, srcPad);
  k_mm<true, false, false, true><<<dim3(FD / 128, (BN * TN) / 128), 256, 0,
                                   stream>>>(srcPad, convW, emb_b,
                                             (float*)d_out, BN * TN, FD,
                                             3 * FD);
}

// Round 13
// 880.914 us; speedup vs baseline: 1.2524x; 1.0388x over previous
//
#include <hip/hip_runtime.h>
#include <hip/hip_bf16.h>

// ---------------------------------------------------------------------------
// Round 13: QKV GEMM on new k_mm8 — 256x256 tile, BK=32, 3-buffer LDS ring
// (96KB), 16-MFMA phases with counted vmcnt(4) held across barriers
// (T2+T3+T4+T5, race-provable variant of the 8-phase template).
// k_pad fused into the final add_ln (dedicated srcPad buffer).
// fattn/k_mm/etc unchanged from R12 (best measured).
// ---------------------------------------------------------------------------

constexpr int BN = 4, TN = 2048, FD = 1024, CP = 200, SN = TN + CP;  // 2248
constexpr int HN = 8, DH = 128, DF = 128, MR = BN * SN;              // 8992
constexpr int SF = 3 * FD;                                           // 3072
constexpr int NT = (SN + 63) / 64;                                   // 36 tiles
constexpr float C2 = 0.12751744f;  // (1/sqrt(128)) * log2(e)

typedef __attribute__((ext_vector_type(8))) short short8;
typedef __attribute__((ext_vector_type(4))) float f32x4;

__device__ __forceinline__ ushort f2b(float f) {
  union { float f; uint u; } v{f};
  return (ushort)((v.u + 0x7fffu + ((v.u >> 16) & 1u)) >> 16);
}
__device__ __forceinline__ float b2f(ushort u) {
  union { uint u; float f; } v{(uint)u << 16};
  return v.f;
}
__device__ __forceinline__ uint cvt_pk_bf16(float a, float b) {
  uint r;
  asm("v_cvt_pk_bf16_f32 %0, %1, %2" : "=v"(r) : "v"(a), "v"(b));
  return r;
}
__device__ __forceinline__ float exp2_fast(float x) {
  float r;
  asm("v_exp_f32 %0, %1" : "=v"(r) : "v"(x));
  return r;
}
__device__ __forceinline__ void gld16(const void* g, void* l) {
  __builtin_amdgcn_global_load_lds(
      (const __attribute__((address_space(1))) void*)g,
      (__attribute__((address_space(3))) void*)l, 16, 0, 0);
}

// ---------------- build src bf16 (row/block) -------------------------------
__global__ __launch_bounds__(256) void k_build(const float* __restrict__ x,
                                               const float* __restrict__ proto,
                                               ushort* __restrict__ srcb) {
  const int row = blockIdx.x;  // 0..MR-1
  const int b = row / SN, s = row % SN;
  const int f = threadIdx.x * 4;
  const size_t o = (size_t)row * FD + f;
  float4 v;
  if (s < TN) {
    v = *(const float4*)(x + ((size_t)b * TN + s) * FD + f);
  } else {
    const int c = s - TN;
    v.x = proto[(size_t)(f + 0) * CP + c];
    v.y = proto[(size_t)(f + 1) * CP + c];
    v.z = proto[(size_t)(f + 2) * CP + c];
    v.w = proto[(size_t)(f + 3) * CP + c];
  }
  ushort4 u{f2b(v.x), f2b(v.y), f2b(v.z), f2b(v.w)};
  *(ushort4*)(srcb + o) = u;
}

// ---------------- flat fp32 -> bf16 (vec4) ---------------------------------
__global__ __launch_bounds__(256) void k_cvt(const float* __restrict__ in,
                                             ushort* __restrict__ out, int n) {
  const int n4 = n >> 2;
  for (int i = blockIdx.x * 256 + threadIdx.x; i < n4; i += gridDim.x * 256) {
    const float4 v = *(const float4*)(in + (size_t)i * 4);
    ushort4 u{f2b(v.x), f2b(v.y), f2b(v.z), f2b(v.w)};
    *(ushort4*)(out + (size_t)i * 4) = u;
  }
}

// ---------------- in_w (L,3F,F) fp32 -> Q/K parts to wInQK, V to wQKV ------
__global__ __launch_bounds__(256) void k_cvt_inw(const float* __restrict__ in,
                                                 ushort* __restrict__ wInQK,
                                                 ushort* __restrict__ wQKV) {
  constexpr size_t FF = (size_t)FD * FD;
  const int n4 = (int)(6 * FF / 4);
  for (int i = blockIdx.x * 256 + threadIdx.x; i < n4; i += gridDim.x * 256) {
    const size_t idx = (size_t)i * 4;
    const float4 v = *(const float4*)(in + idx);
    ushort4 u{f2b(v.x), f2b(v.y), f2b(v.z), f2b(v.w)};
    const int l = (int)(idx / (3 * FF));
    const size_t r = idx % (3 * FF);
    ushort* dst = (r >= 2 * FF) ? (wQKV + l * 3 * FF + r)
                                : (wInQK + l * 2 * FF + r);
    *(ushort4*)dst = u;
  }
}

// ---------------- transpose-convert FxF fp32 -> bf16, z = qk*2+l -----------
__global__ __launch_bounds__(256) void k_cvtT(const float* __restrict__ wq,
                                              const float* __restrict__ wk,
                                              ushort* __restrict__ wT) {
  const int z = blockIdx.z;  // qk*2 + l
  const int qk = z >> 1, l = z & 1;
  const float* W = (qk ? wk : wq) + (size_t)l * FD * FD;
  ushort* WT = wT + (size_t)z * FD * FD;
  __shared__ float t[32][33];
  const int tx = threadIdx.x & 31, ty = threadIdx.x >> 5;
  const int x0 = blockIdx.x * 32, y0 = blockIdx.y * 32;
#pragma unroll
  for (int dy = 0; dy < 4; ++dy)
    t[ty + dy * 8][tx] = W[(size_t)(y0 + ty + dy * 8) * FD + x0 + tx];
  __syncthreads();
#pragma unroll
  for (int dy = 0; dy < 4; ++dy)
    WT[(size_t)(x0 + ty + dy * 8) * FD + y0 + tx] = f2b(t[tx][ty + dy * 8]);
}

// ---------------- per-(b,h) transpose V (from packed QKV) ------------------
__global__ __launch_bounds__(256) void k_vT(const ushort* __restrict__ V,
                                            ushort* __restrict__ Vt) {
  __shared__ ushort t[32][34];
  const int tx = threadIdx.x & 31, ty = threadIdx.x >> 5;
  const int s0 = blockIdx.x * 32, d0 = blockIdx.y * 32, bh = blockIdx.z;
  const int b = bh >> 3, h = bh & 7;
#pragma unroll
  for (int dy = 0; dy < 4; ++dy) {
    const int s = min(s0 + ty + dy * 8, SN - 1);
    t[ty + dy * 8][tx] = V[((size_t)b * SN + s) * SF + h * DH + d0 + tx];
  }
  __syncthreads();
#pragma unroll
  for (int dy = 0; dy < 4; ++dy) {
    const int s = s0 + tx;
    if (s < SN)
      Vt[((size_t)bh * DH + d0 + ty + dy * 8) * SN + s] = t[tx][ty + dy * 8];
  }
}

// ---------------- conv weight repack: cw[o][tau*F+i] = W[o][i][tau] --------
__global__ __launch_bounds__(256) void k_convw(const float* __restrict__ W,
                                               ushort* __restrict__ out) {
  const int n = FD * FD * 3;
  for (int idx = blockIdx.x * 256 + threadIdx.x; idx < n;
       idx += gridDim.x * 256) {
    const int o = idx / (FD * 3);
    const int rem = idx % (FD * 3);
    const int tau = rem >> 10, i = rem & 1023;
    out[idx] = f2b(W[(size_t)o * (FD * 3) + i * 3 + tau]);
  }
}

// ---------------- zero the pad boundary rows of srcPad ---------------------
__global__ __launch_bounds__(256) void k_zpad(ushort* __restrict__ pad) {
  const int r = blockIdx.x ? TN + 1 : 0;
  const int b = blockIdx.y;
  ushort4 z{0, 0, 0, 0};
  *(ushort4*)(pad + ((size_t)b * (TN + 2) + r) * FD + threadIdx.x * 4) = z;
}

// ---------------- effective bias (z<2) + V-bias copy (z==2) ----------------
__global__ __launch_bounds__(256) void k_beff(const float* __restrict__ in_w,
                                              const float* __restrict__ bq,
                                              const float* __restrict__ bk,
                                              const float* __restrict__ in_b,
                                              float* __restrict__ out) {
  const int n = blockIdx.x, l = blockIdx.y, qk = blockIdx.z;
  const int tid = threadIdx.x;
  if (qk == 2) {
    if (tid == 0)
      out[l * 3 * FD + 2 * FD + n] = in_b[l * 3 * FD + 2 * FD + n];
    return;
  }
  const float* Win = in_w + (size_t)(l * 3 + qk) * FD * FD;
  const float* bv = (qk ? bk : bq) + (size_t)l * FD;
  float s = 0.f;
  for (int j = tid; j < FD; j += 256) s += Win[(size_t)n * FD + j] * bv[j];
  __shared__ float red[4];
#pragma unroll
  for (int o = 32; o; o >>= 1) s += __shfl_xor(s, o);
  if ((tid & 63) == 0) red[tid >> 6] = s;
  __syncthreads();
  if (tid == 0)
    out[l * 3 * FD + qk * FD + n] =
        red[0] + red[1] + red[2] + red[3] + in_b[l * 3 * FD + qk * FD + n];
}

// ---------------- bf16 MFMA GEMM, 128x128 (m97 structure) ------------------
template <bool RELU, bool BF16OUT, bool PREP4 = false, bool CONV = false>
__global__ __launch_bounds__(256) void k_mm(const ushort* __restrict__ A,
                                            const ushort* __restrict__ W,
                                            const float* __restrict__ bias,
                                            void* __restrict__ Cv,
                                            int M, int N, int K) {
  constexpr size_t FF = (size_t)FD * FD;
  if (PREP4) {
    const int z = blockIdx.z;  // l*2 + qk
    A += (size_t)z * FF;
    W += (size_t)(((z & 1) * 2) + (z >> 1)) * FF;   // qk*2 + l
    Cv = (void*)((ushort*)Cv + (size_t)((z >> 1) * 3 + (z & 1)) * FF);
  }
  __shared__ __align__(16) ushort As[128 * 32];
  __shared__ __align__(16) ushort Ws[128 * 32];
  const int tid = threadIdx.x;
  const int lane = tid & 63, wv = tid >> 6;
  const int l15 = lane & 15, g = lane >> 4;
  const int wr = wv >> 1, wc = wv & 1;
  int bx = blockIdx.x, by = blockIdx.y;
  const int nwg = gridDim.x * gridDim.y;
  if ((nwg & 7) == 0) {  // bijective XCD swizzle (T1)
    int bid = by * gridDim.x + bx;
    bid = (bid & 7) * (nwg >> 3) + (bid >> 3);
    bx = bid % gridDim.x;
    by = bid / gridDim.x;
  }
  const int m0 = by * 128, n0 = bx * 128;
  f32x4 acc[4][4];
#pragma unroll
  for (int i = 0; i < 4; ++i)
#pragma unroll
    for (int j = 0; j < 4; ++j) acc[i][j] = (f32x4){0.f, 0.f, 0.f, 0.f};

  for (int k0 = 0; k0 < K; k0 += 32) {
#pragma unroll
    for (int j = 0; j < 2; ++j) {
      const int u = j * 256 + wv * 64 + lane;
      const int r = u >> 2, c = (u & 3) * 8;
      const ushort* ga;
      if (CONV) {
        const int rm = m0 + r;  // M multiple of 128
        const int bb = rm >> 11, tt = rm & 2047;
        ga = A + (size_t)(bb * (TN + 2) + tt + (k0 >> 10)) * FD + (k0 & 1023) +
             c;
      } else {
        ga = A + (size_t)min(m0 + r, M - 1) * K + k0 + c;
      }
      gld16(ga, As + (size_t)u * 8);
    }
#pragma unroll
    for (int j = 0; j < 2; ++j) {
      const int u = j * 256 + wv * 64 + lane;
      const int r = u >> 2, c = (u & 3) * 8;
      gld16(W + (size_t)(n0 + r) * K + k0 + c, Ws + (size_t)u * 8);
    }
    __syncthreads();
    short8 af[4], bfr[4];
#pragma unroll
    for (int i = 0; i < 4; ++i)
      af[i] = *(const short8*)(As + (wr * 64 + i * 16 + l15) * 32 + g * 8);
#pragma unroll
    for (int j = 0; j < 4; ++j)
      bfr[j] = *(const short8*)(Ws + (wc * 64 + j * 16 + l15) * 32 + g * 8);
    __builtin_amdgcn_s_setprio(1);
#pragma unroll
    for (int i = 0; i < 4; ++i)
#pragma unroll
      for (int j = 0; j < 4; ++j)
        acc[i][j] = __builtin_amdgcn_mfma_f32_16x16x32_bf16(af[i], bfr[j],
                                                            acc[i][j], 0, 0, 0);
    __builtin_amdgcn_s_setprio(0);
    __syncthreads();
  }
#pragma unroll
  for (int i = 0; i < 4; ++i) {
#pragma unroll
    for (int r = 0; r < 4; ++r) {
      const int row = m0 + wr * 64 + i * 16 + g * 4 + r;
      if (!CONV && row >= M) continue;
#pragma unroll
      for (int j = 0; j < 4; ++j) {
        const int col = n0 + wc * 64 + j * 16 + l15;
        float v = acc[i][j][r];
        if (bias) v += bias[col];
        if (RELU || CONV) v = fmaxf(v, 0.f);
        if (CONV) {
          const int bb = row >> 11, tt = row & 2047;
          ((float*)Cv)[((size_t)(bb * FD + col)) * TN + tt] = v;
        } else if (BF16OUT) {
          ((ushort*)Cv)[(size_t)row * N + col] = f2b(v);
        } else {
          ((float*)Cv)[(size_t)row * N + col] = v;
        }
      }
    }
  }
}

// ---------------- k_mm8: 256x256, BK=32, 3-buffer ring, counted vmcnt ------
// 512 thr = 8 waves (2M x 4N); wave owns 128x64 (8m x 4n frags).
// Per K-tile: 2 phases x 16 MFMA. While computing tile t (buf t%3), stage
// tile t+2 into buf (t+2)%3 (its old occupant t-3 drained before t-2 began).
// vmcnt(4) per tile end = tile t+2's 4 load-instrs stay in flight (T4).
// Slot-XOR swizzle s = chunk ^ ((row>>1)&3): 2-way bank access (free).
__global__ __launch_bounds__(512, 1) void k_mm8(const ushort* __restrict__ A,
                                                const ushort* __restrict__ W,
                                                const float* __restrict__ bias,
                                                ushort* __restrict__ C,
                                                int M, int N, int K) {
  __shared__ __align__(16) ushort As[3][256 * 32];
  __shared__ __align__(16) ushort Bs[3][256 * 32];
  const int tid = threadIdx.x;
  const int lane = tid & 63, wv = tid >> 6;
  const int l15 = lane & 15, g = lane >> 4;
  const int wr = wv >> 2, wc = wv & 3;
  int bx = blockIdx.x, by = blockIdx.y;
  const int nwg = gridDim.x * gridDim.y;
  if ((nwg & 7) == 0) {  // bijective XCD swizzle (T1)
    int bid = by * gridDim.x + bx;
    bid = (bid & 7) * (nwg >> 3) + (bid >> 3);
    bx = bid % gridDim.x;
    by = bid / gridDim.x;
  }
  const int m0 = by * 256, n0 = bx * 256;
  const int NKt = K >> 5;

  f32x4 acc[8][4];
#pragma unroll
  for (int i = 0; i < 8; ++i)
#pragma unroll
    for (int j = 0; j < 4; ++j) acc[i][j] = (f32x4){0.f, 0.f, 0.f, 0.f};

  // stage A (or B) of K-tile kt into buf kt%3: 2 gld16/thread each
  auto stageA = [&](int kt) {
    ushort* dst = As[kt % 3];
    const int kb = kt * 32;
#pragma unroll
    for (int j = 0; j < 2; ++j) {
      const int u = j * 512 + tid;        // 0..1023
      const int row = u >> 2, s = u & 3;  // row 0..255, 16B slot 0..3
      const int c = s ^ ((row >> 1) & 3);
      gld16(A + (size_t)min(m0 + row, M - 1) * K + kb + c * 8,
            dst + row * 32 + s * 8);
    }
  };
  auto stageB = [&](int kt) {
    ushort* dst = Bs[kt % 3];
    const int kb = kt * 32;
#pragma unroll
    for (int j = 0; j < 2; ++j) {
      const int u = j * 512 + tid;
      const int row = u >> 2, s = u & 3;
      const int c = s ^ ((row >> 1) & 3);
      gld16(W + (size_t)(n0 + row) * K + kb + c * 8, dst + row * 32 + s * 8);
    }
  };

  // prologue: tiles 0 and 1 fully staged; wait tile 0 (4 newest may fly)
  stageA(0); stageB(0); stageA(1); stageB(1);
  asm volatile("s_waitcnt vmcnt(4)" ::: "memory");
  __builtin_amdgcn_s_barrier();

  for (int t = 0; t < NKt; ++t) {
    const int d = t % 3;
    const ushort* Ab = As[d];
    const ushort* Bb = Bs[d];
    short8 bfr[4];
    // ---------------- phase 0: m-frags 0..3 -------------------------------
    {
      short8 afr[4];
#pragma unroll
      for (int mi = 0; mi < 4; ++mi) {
        const int row = wr * 128 + mi * 16 + l15;
        afr[mi] = *(const short8*)(Ab + row * 32 +
                                   ((g ^ ((row >> 1) & 3)) << 3));
      }
#pragma unroll
      for (int ni = 0; ni < 4; ++ni) {
        const int row = wc * 64 + ni * 16 + l15;
        bfr[ni] = *(const short8*)(Bb + row * 32 +
                                   ((g ^ ((row >> 1) & 3)) << 3));
      }
      if (t + 2 < NKt) stageA(t + 2);
      __builtin_amdgcn_s_barrier();
      asm volatile("s_waitcnt lgkmcnt(0)" ::: "memory");
      __builtin_amdgcn_sched_barrier(0);
      __builtin_amdgcn_s_setprio(1);
#pragma unroll
      for (int mi = 0; mi < 4; ++mi)
#pragma unroll
        for (int ni = 0; ni < 4; ++ni)
          acc[mi][ni] = __builtin_amdgcn_mfma_f32_16x16x32_bf16(
              afr[mi], bfr[ni], acc[mi][ni], 0, 0, 0);
      __builtin_amdgcn_s_setprio(0);
      __builtin_amdgcn_s_barrier();
    }
    // ---------------- phase 1: m-frags 4..7 -------------------------------
    {
      short8 afr[4];
#pragma unroll
      for (int mi = 0; mi < 4; ++mi) {
        const int row = wr * 128 + (4 + mi) * 16 + l15;
        afr[mi] = *(const short8*)(Ab + row * 32 +
                                   ((g ^ ((row >> 1) & 3)) << 3));
      }
      if (t + 2 < NKt) stageB(t + 2);
      __builtin_amdgcn_s_barrier();
      asm volatile("s_waitcnt lgkmcnt(0)" ::: "memory");
      __builtin_amdgcn_sched_barrier(0);
      __builtin_amdgcn_s_setprio(1);
#pragma unroll
      for (int mi = 0; mi < 4; ++mi)
#pragma unroll
        for (int ni = 0; ni < 4; ++ni)
          acc[4 + mi][ni] = __builtin_amdgcn_mfma_f32_16x16x32_bf16(
              afr[mi], bfr[ni], acc[4 + mi][ni], 0, 0, 0);
      __builtin_amdgcn_s_setprio(0);
      if (t + 1 < NKt) {
        if (t + 2 < NKt)
          asm volatile("s_waitcnt vmcnt(4)" ::: "memory");  // tile t+1 landed
        else
          asm volatile("s_waitcnt vmcnt(0)" ::: "memory");
      }
      __builtin_amdgcn_s_barrier();
    }
  }

  // epilogue
#pragma unroll
  for (int mi = 0; mi < 8; ++mi) {
#pragma unroll
    for (int r = 0; r < 4; ++r) {
      const int row = m0 + wr * 128 + mi * 16 + g * 4 + r;
      if (row >= M) continue;
#pragma unroll
      for (int ni = 0; ni < 4; ++ni) {
        const int col = n0 + wc * 64 + ni * 16 + l15;
        float v = acc[mi][ni][r];
        if (bias) v += bias[col];
        C[(size_t)row * N + col] = f2b(v);
      }
    }
  }
}

// ---------------- flash attention: R6-exact + bh-major XCD remap -----------
__global__ __launch_bounds__(256) void k_fattn(const ushort* __restrict__ Qg,
                                               const ushort* __restrict__ Kg,
                                               const ushort* __restrict__ Vt,
                                               ushort* __restrict__ Og) {
  __shared__ __align__(16) ushort Ks[64 * 128];
  __shared__ __align__(16) ushort Vs[128 * 64];
  __shared__ __align__(16) ushort Ps[4][16 * 64];
  const int tid = threadIdx.x, lane = tid & 63, wv = tid >> 6;
  const int l15 = lane & 15, g = lane >> 4;
  const int flat = blockIdx.x + NT * (blockIdx.y + HN * blockIdx.z);
  const int xcd = flat & 7, slot = flat >> 3;   // slot 0..143
  const int grp = xcd + 8 * (slot / NT);        // bh 0..31
  const int qt = slot % NT;
  const int b = grp >> 3, h = grp & 7, q0 = qt * 64;
  const size_t rowBase = (size_t)b * SN;
  const int hoff = h * DH;
  const size_t vbase = (size_t)grp * DH * SN;

  short8 qf[4];
  const int qrow = min(q0 + wv * 16 + l15, SN - 1);
#pragma unroll
  for (int c = 0; c < 4; ++c)
    qf[c] = *(const short8*)(Qg + (rowBase + qrow) * SF + hoff + c * 32 + g * 8);

  short8 onesf;
#pragma unroll
  for (int i = 0; i < 8; ++i) onesf[i] = (short)0x3F80;  // bf16 1.0

  f32x4 o[8];
#pragma unroll
  for (int dt = 0; dt < 8; ++dt) o[dt] = (f32x4){0.f, 0.f, 0.f, 0.f};
  f32x4 lacc = (f32x4){0.f, 0.f, 0.f, 0.f};  // MFMA row-sum of P
  const char* KsB = (const char*)Ks;
  const char* VsB = (const char*)Vs;
  char* PsB = (char*)&Ps[wv][0];

  for (int t = 0; t < NT; ++t) {
    const int kv0 = t * 64;
    const bool tl = (t == NT - 1);
    if (tl) {
#pragma unroll
      for (int j = 0; j < 4; ++j) {
        const int su = j * 256 + tid;
        const int row = su >> 4, s = su & 15;
        const int c16 = s ^ (row & 7);
        const int krow = min(kv0 + row, SN - 1);
        gld16(Kg + (rowBase + krow) * SF + hoff + c16 * 8, Ks + (size_t)su * 8);
      }
#pragma unroll
      for (int j = 0; j < 4; ++j) {
        const int su = j * 256 + tid;
        const int row = su >> 3, s = su & 7;
        const int cc = s ^ (row & 7);
        const int kvc = min(kv0 + cc * 8, SN - 8);
        gld16(Vt + vbase + (size_t)row * SN + kvc, Vs + (size_t)su * 8);
      }
    } else {
#pragma unroll
      for (int j = 0; j < 4; ++j) {
        const int su = j * 256 + tid;
        const int row = su >> 4, s = su & 15;
        const int c16 = s ^ (row & 7);
        gld16(Kg + (rowBase + kv0 + row) * SF + hoff + c16 * 8,
              Ks + (size_t)su * 8);
      }
#pragma unroll
      for (int j = 0; j < 4; ++j) {
        const int su = j * 256 + tid;
        const int row = su >> 3, s = su & 7;
        const int cc = s ^ (row & 7);
        gld16(Vt + vbase + (size_t)row * SN + kv0 + cc * 8,
              Vs + (size_t)su * 8);
      }
    }
    __syncthreads();

    // S^T = K · Q^T
    f32x4 st[4];
    __builtin_amdgcn_s_setprio(1);
#pragma unroll
    for (int kt = 0; kt < 4; ++kt) {
      f32x4 s4 = (f32x4){0.f, 0.f, 0.f, 0.f};
      const int row = kt * 16 + l15;
#pragma unroll
      for (int c = 0; c < 4; ++c) {
        const short8 kf = *(const short8*)(
            KsB + row * 256 + (((c * 4 + g) ^ (row & 7)) << 4));
        s4 = __builtin_amdgcn_mfma_f32_16x16x32_bf16(kf, qf[c], s4, 0, 0, 0);
      }
      st[kt] = s4;
    }
    __builtin_amdgcn_s_setprio(0);

    // no-max softmax: p = 2^(C2*s); mask only on tail tile
    float pfl[16];
    if (tl) {
#pragma unroll
      for (int kt = 0; kt < 4; ++kt)
#pragma unroll
        for (int r = 0; r < 4; ++r) {
          const int kvg = kv0 + kt * 16 + g * 4 + r;
          pfl[kt * 4 + r] = (kvg < SN) ? exp2_fast(C2 * st[kt][r]) : 0.f;
        }
    } else {
#pragma unroll
      for (int i = 0; i < 16; ++i)
        pfl[i] = exp2_fast(C2 * st[i >> 2][i & 3]);
    }

    // write P: row l15, 16B slots XOR-swizzled by (l15&7)
#pragma unroll
    for (int kt = 0; kt < 4; ++kt) {
      const uint lo = cvt_pk_bf16(pfl[kt * 4 + 0], pfl[kt * 4 + 1]);
      const uint hi = cvt_pk_bf16(pfl[kt * 4 + 2], pfl[kt * 4 + 3]);
      const int slot = (kt * 2 + (g >> 1)) ^ (l15 & 7);
      *(uint2*)(PsB + l15 * 128 + slot * 16 + (g & 1) * 8) = make_uint2(lo, hi);
    }

    // PV: O += P · V ; lacc += P · 1 (row-sum via matrix pipe)
    __builtin_amdgcn_s_setprio(1);
#pragma unroll
    for (int c2 = 0; c2 < 2; ++c2) {
      const int pslot = (c2 * 4 + g) ^ (l15 & 7);
      const short8 pf = *(const short8*)(PsB + l15 * 128 + pslot * 16);
      lacc = __builtin_amdgcn_mfma_f32_16x16x32_bf16(pf, onesf, lacc, 0, 0, 0);
#pragma unroll
      for (int dt = 0; dt < 8; ++dt) {
        const int row = dt * 16 + l15;
        const short8 vf = *(const short8*)(
            VsB + row * 128 + (((c2 * 4 + g) ^ (row & 7)) << 4));
        o[dt] = __builtin_amdgcn_mfma_f32_16x16x32_bf16(pf, vf, o[dt], 0, 0, 0);
      }
    }
    __builtin_amdgcn_s_setprio(0);
    __syncthreads();
  }

  float ir[4];
#pragma unroll
  for (int r = 0; r < 4; ++r) ir[r] = 1.f / lacc[r];
#pragma unroll
  for (int r = 0; r < 4; ++r) {
    const int orow = q0 + wv * 16 + g * 4 + r;
    if (orow >= SN) continue;
#pragma unroll
    for (int dt = 0; dt < 8; ++dt)
      Og[(rowBase + orow) * FD + hoff + dt * 16 + l15] = f2b(o[dt][r] * ir[r]);
  }
}

// ---------------- fused residual + LayerNorm (+optional pad write) ---------
template <bool WPAD>
__global__ __launch_bounds__(256) void k_add_ln(ushort* __restrict__ sb,
                                                const ushort* __restrict__ d,
                                                const float* __restrict__ g,
                                                const float* __restrict__ be,
                                                ushort* __restrict__ pad) {
  __shared__ float red[4];
  const int row = blockIdx.x;
  const int tid = threadIdx.x;
  const int c = tid * 4;
  const size_t off = (size_t)row * FD + c;
  const ushort4 sv = *(const ushort4*)(sb + off);
  const ushort4 dv = *(const ushort4*)(d + off);
  float v[4] = {b2f(sv.x) + b2f(dv.x), b2f(sv.y) + b2f(dv.y),
                b2f(sv.z) + b2f(dv.z), b2f(sv.w) + b2f(dv.w)};
  float sum = v[0] + v[1] + v[2] + v[3];
#pragma unroll
  for (int o = 32; o; o >>= 1) sum += __shfl_xor(sum, o);
  if ((tid & 63) == 0) red[tid >> 6] = sum;
  __syncthreads();
  sum = red[0] + red[1] + red[2] + red[3];
  const float mu = sum * (1.f / FD);
  float vs = 0.f;
#pragma unroll
  for (int i = 0; i < 4; ++i) {
    const float t = v[i] - mu;
    vs += t * t;
  }
  __syncthreads();
#pragma unroll
  for (int o = 32; o; o >>= 1) vs += __shfl_xor(vs, o);
  if ((tid & 63) == 0) red[tid >> 6] = vs;
  __syncthreads();
  vs = red[0] + red[1] + red[2] + red[3];
  const float rstd = rsqrtf(vs * (1.f / FD) + 1e-5f);
  const float4 gv = *(const float4*)(g + c);
  const float4 bv = *(const float4*)(be + c);
  ushort4 u{f2b((v[0] - mu) * rstd * gv.x + bv.x),
            f2b((v[1] - mu) * rstd * gv.y + bv.y),
            f2b((v[2] - mu) * rstd * gv.z + bv.z),
            f2b((v[3] - mu) * rstd * gv.w + bv.w)};
  *(ushort4*)(sb + off) = u;
  if (WPAD) {
    const int b = row / SN, s = row % SN;
    if (s < TN)
      *(ushort4*)(pad + ((size_t)(b * (TN + 2) + s + 1)) * FD + c) = u;
  }
}

// ---------------------------------------------------------------------------
extern "C" void kernel_launch(void* const* d_in, const int* in_sizes, int n_in,
                              void* d_out, int out_size, void* d_ws,
                              size_t ws_size, hipStream_t stream) {
  const float* x      = (const float*)d_in[0];
  const float* proto  = (const float*)d_in[1];
  const float* wq     = (const float*)d_in[2];
  const float* bq     = (const float*)d_in[3];
  const float* wk     = (const float*)d_in[4];
  const float* bk     = (const float*)d_in[5];
  const float* in_w   = (const float*)d_in[6];
  const float* in_b   = (const float*)d_in[7];
  const float* out_w  = (const float*)d_in[8];
  const float* out_b  = (const float*)d_in[9];
  const float* l1_w   = (const float*)d_in[10];
  const float* l1_b   = (const float*)d_in[11];
  const float* l2_w   = (const float*)d_in[12];
  const float* l2_b   = (const float*)d_in[13];
  const float* ln1_g  = (const float*)d_in[14];
  const float* ln1_b  = (const float*)d_in[15];
  const float* ln2_g  = (const float*)d_in[16];
  const float* ln2_b  = (const float*)d_in[17];
  const float* emb_w  = (const float*)d_in[18];
  const float* emb_b  = (const float*)d_in[19];

  char* p = (char*)d_ws;
  auto take = [&](size_t bytes) {
    char* r = p;
    p += (bytes + 255) & ~(size_t)255;
    return r;
  };
  const size_t MF = (size_t)MR * FD;
  const size_t FF = (size_t)FD * FD;
  ushort* srcb   = (ushort*)take(MF * 2);
  ushort* bQKV   = (ushort*)take((size_t)MR * SF * 2);  // 55 MB, multi-aliased
  ushort* bVt    = (ushort*)take((size_t)BN * HN * DH * SN * 2);
  ushort* bO     = (ushort*)take(MF * 2);
  ushort* bFF    = (ushort*)take((size_t)MR * DF * 2);
  ushort* wQKV   = (ushort*)take((size_t)2 * 3 * FF * 2);  // packed weights
  ushort* wOut   = (ushort*)take((size_t)2 * FF * 2);
  ushort* wL1    = (ushort*)take((size_t)2 * DF * FD * 2);
  ushort* wL2    = (ushort*)take((size_t)2 * FD * DF * 2);
  float*  bqkv   = (float*)take((size_t)2 * SF * 4);
  ushort* srcPad = (ushort*)take((size_t)BN * (TN + 2) * FD * 2);  // dedicated
  ushort* convW  = (ushort*)take((size_t)3 * FF * 2);              // dedicated
  // aliases inside bQKV (lifetimes disjoint from activation use):
  ushort* wT    = bQKV;             // prep: 4 * F*F bf16
  ushort* wInQK = bQKV + 4 * FF;    // prep: 4 * F*F bf16
  ushort* bOut  = bQKV;             // post-attn / post-FFN2 bf16

  // ---- prep (all weight-only work hoisted, consolidated) ----
  k_build<<<MR, 256, 0, stream>>>(x, proto, srcb);
  k_cvt_inw<<<2048, 256, 0, stream>>>(in_w, wInQK, wQKV);
  k_cvt<<<1024, 256, 0, stream>>>(out_w, wOut, 2 * FF);
  k_cvt<<<256, 256, 0, stream>>>(l1_w, wL1, 2 * DF * FD);
  k_cvt<<<256, 256, 0, stream>>>(l2_w, wL2, 2 * FD * DF);
  k_cvtT<<<dim3(32, 32, 4), 256, 0, stream>>>(wq, wk, wT);
  k_mm<false, true, true><<<dim3(8, 8, 4), 256, 0, stream>>>(
      wInQK, wT, nullptr, wQKV, FD, FD, FD);
  k_beff<<<dim3(FD, 2, 3), 256, 0, stream>>>(in_w, bq, bk, in_b, bqkv);
  k_convw<<<1024, 256, 0, stream>>>(emb_w, convW);
  k_zpad<<<dim3(2, BN), 256, 0, stream>>>(srcPad);

  const int MB = (MR + 127) / 128;    // 71 (128-tiles)
  const int MB2 = (MR + 255) / 256;   // 36 (256-tiles)

  // ---- layers ----
  for (int l = 0; l < 2; ++l) {
    k_mm8<<<dim3(SF / 256, MB2), 512, 0, stream>>>(
        srcb, wQKV + (size_t)l * 3 * FF, bqkv + (size_t)l * SF, bQKV, MR, SF,
        FD);
    k_vT<<<dim3((SN + 31) / 32, DH / 32, BN * HN), 256, 0, stream>>>(
        bQKV + 2 * FD, bVt);
    k_fattn<<<dim3(NT, HN, BN), 256, 0, stream>>>(bQKV, bQKV + FD, bVt, bO);
    k_mm<false, true><<<dim3(FD / 128, MB), 256, 0, stream>>>(
        bO, wOut + (size_t)l * FF, out_b + (size_t)l * FD, bOut, MR, FD, FD);
    k_add_ln<false><<<MR, 256, 0, stream>>>(srcb, bOut,
                                            ln1_g + (size_t)l * FD,
                                            ln1_b + (size_t)l * FD, nullptr);
    k_mm<true, true><<<dim3(DF / 128, MB), 256, 0, stream>>>(
        srcb, wL1 + (size_t)l * DF * FD, l1_b + (size_t)l * DF, bFF, MR, DF,
        FD);
    k_mm<false, true><<<dim3(FD / 128, MB), 256, 0, stream>>>(
        bFF, wL2 + (size_t)l * FD * DF, l2_b + (size_t)l * FD, bOut, MR, FD,
        DF);
    if (l == 1)
      k_add_ln<true><<<MR, 256, 0, stream>>>(srcb, bOut,
                                             ln2_g + (size_t)l * FD,
                                             ln2_b + (size_t)l * FD, srcPad);
    else
      k_add_ln<false><<<MR, 256, 0, stream>>>(srcb, bOut,
                                              ln2_g + (size_t)l * FD,
                                              ln2_b + (size_t)l * FD, nullptr);
  }

  // ---- conv head ----
  k_mm<true, false, false, true><<<dim3(FD / 128, (BN * TN) / 128), 256, 0,
                                   stream>>>(srcPad, convW, emb_b,
                                             (float*)d_out, BN * TN, FD,
                                             3 * FD);
}

// Round 14
// 849.831 us; speedup vs baseline: 1.2982x; 1.0366x over previous
//
#include <hip/hip_runtime.h>
#include <hip/hip_bf16.h>

// ---------------------------------------------------------------------------
// Round 14: k_mm8b (256x128, 3-ring, vmcnt(3), 72KB LDS -> 2 blocks/CU) for
// attn-out and conv GEMMs. QKV stays on k_mm8 (256x256). fattn frozen (R12).
// ---------------------------------------------------------------------------

constexpr int BN = 4, TN = 2048, FD = 1024, CP = 200, SN = TN + CP;  // 2248
constexpr int HN = 8, DH = 128, DF = 128, MR = BN * SN;              // 8992
constexpr int SF = 3 * FD;                                           // 3072
constexpr int NT = (SN + 63) / 64;                                   // 36 tiles
constexpr float C2 = 0.12751744f;  // (1/sqrt(128)) * log2(e)

typedef __attribute__((ext_vector_type(8))) short short8;
typedef __attribute__((ext_vector_type(4))) float f32x4;

__device__ __forceinline__ ushort f2b(float f) {
  union { float f; uint u; } v{f};
  return (ushort)((v.u + 0x7fffu + ((v.u >> 16) & 1u)) >> 16);
}
__device__ __forceinline__ float b2f(ushort u) {
  union { uint u; float f; } v{(uint)u << 16};
  return v.f;
}
__device__ __forceinline__ uint cvt_pk_bf16(float a, float b) {
  uint r;
  asm("v_cvt_pk_bf16_f32 %0, %1, %2" : "=v"(r) : "v"(a), "v"(b));
  return r;
}
__device__ __forceinline__ float exp2_fast(float x) {
  float r;
  asm("v_exp_f32 %0, %1" : "=v"(r) : "v"(x));
  return r;
}
__device__ __forceinline__ void gld16(const void* g, void* l) {
  __builtin_amdgcn_global_load_lds(
      (const __attribute__((address_space(1))) void*)g,
      (__attribute__((address_space(3))) void*)l, 16, 0, 0);
}

// ---------------- build src bf16 (row/block) -------------------------------
__global__ __launch_bounds__(256) void k_build(const float* __restrict__ x,
                                               const float* __restrict__ proto,
                                               ushort* __restrict__ srcb) {
  const int row = blockIdx.x;  // 0..MR-1
  const int b = row / SN, s = row % SN;
  const int f = threadIdx.x * 4;
  const size_t o = (size_t)row * FD + f;
  float4 v;
  if (s < TN) {
    v = *(const float4*)(x + ((size_t)b * TN + s) * FD + f);
  } else {
    const int c = s - TN;
    v.x = proto[(size_t)(f + 0) * CP + c];
    v.y = proto[(size_t)(f + 1) * CP + c];
    v.z = proto[(size_t)(f + 2) * CP + c];
    v.w = proto[(size_t)(f + 3) * CP + c];
  }
  ushort4 u{f2b(v.x), f2b(v.y), f2b(v.z), f2b(v.w)};
  *(ushort4*)(srcb + o) = u;
}

// ---------------- flat fp32 -> bf16 (vec4) ---------------------------------
__global__ __launch_bounds__(256) void k_cvt(const float* __restrict__ in,
                                             ushort* __restrict__ out, int n) {
  const int n4 = n >> 2;
  for (int i = blockIdx.x * 256 + threadIdx.x; i < n4; i += gridDim.x * 256) {
    const float4 v = *(const float4*)(in + (size_t)i * 4);
    ushort4 u{f2b(v.x), f2b(v.y), f2b(v.z), f2b(v.w)};
    *(ushort4*)(out + (size_t)i * 4) = u;
  }
}

// ---------------- in_w (L,3F,F) fp32 -> Q/K parts to wInQK, V to wQKV ------
__global__ __launch_bounds__(256) void k_cvt_inw(const float* __restrict__ in,
                                                 ushort* __restrict__ wInQK,
                                                 ushort* __restrict__ wQKV) {
  constexpr size_t FF = (size_t)FD * FD;
  const int n4 = (int)(6 * FF / 4);
  for (int i = blockIdx.x * 256 + threadIdx.x; i < n4; i += gridDim.x * 256) {
    const size_t idx = (size_t)i * 4;
    const float4 v = *(const float4*)(in + idx);
    ushort4 u{f2b(v.x), f2b(v.y), f2b(v.z), f2b(v.w)};
    const int l = (int)(idx / (3 * FF));
    const size_t r = idx % (3 * FF);
    ushort* dst = (r >= 2 * FF) ? (wQKV + l * 3 * FF + r)
                                : (wInQK + l * 2 * FF + r);
    *(ushort4*)dst = u;
  }
}

// ---------------- transpose-convert FxF fp32 -> bf16, z = qk*2+l -----------
__global__ __launch_bounds__(256) void k_cvtT(const float* __restrict__ wq,
                                              const float* __restrict__ wk,
                                              ushort* __restrict__ wT) {
  const int z = blockIdx.z;  // qk*2 + l
  const int qk = z >> 1, l = z & 1;
  const float* W = (qk ? wk : wq) + (size_t)l * FD * FD;
  ushort* WT = wT + (size_t)z * FD * FD;
  __shared__ float t[32][33];
  const int tx = threadIdx.x & 31, ty = threadIdx.x >> 5;
  const int x0 = blockIdx.x * 32, y0 = blockIdx.y * 32;
#pragma unroll
  for (int dy = 0; dy < 4; ++dy)
    t[ty + dy * 8][tx] = W[(size_t)(y0 + ty + dy * 8) * FD + x0 + tx];
  __syncthreads();
#pragma unroll
  for (int dy = 0; dy < 4; ++dy)
    WT[(size_t)(x0 + ty + dy * 8) * FD + y0 + tx] = f2b(t[tx][ty + dy * 8]);
}

// ---------------- per-(b,h) transpose V (from packed QKV) ------------------
__global__ __launch_bounds__(256) void k_vT(const ushort* __restrict__ V,
                                            ushort* __restrict__ Vt) {
  __shared__ ushort t[32][34];
  const int tx = threadIdx.x & 31, ty = threadIdx.x >> 5;
  const int s0 = blockIdx.x * 32, d0 = blockIdx.y * 32, bh = blockIdx.z;
  const int b = bh >> 3, h = bh & 7;
#pragma unroll
  for (int dy = 0; dy < 4; ++dy) {
    const int s = min(s0 + ty + dy * 8, SN - 1);
    t[ty + dy * 8][tx] = V[((size_t)b * SN + s) * SF + h * DH + d0 + tx];
  }
  __syncthreads();
#pragma unroll
  for (int dy = 0; dy < 4; ++dy) {
    const int s = s0 + tx;
    if (s < SN)
      Vt[((size_t)bh * DH + d0 + ty + dy * 8) * SN + s] = t[tx][ty + dy * 8];
  }
}

// ---------------- conv weight repack: cw[o][tau*F+i] = W[o][i][tau] --------
__global__ __launch_bounds__(256) void k_convw(const float* __restrict__ W,
                                               ushort* __restrict__ out) {
  const int n = FD * FD * 3;
  for (int idx = blockIdx.x * 256 + threadIdx.x; idx < n;
       idx += gridDim.x * 256) {
    const int o = idx / (FD * 3);
    const int rem = idx % (FD * 3);
    const int tau = rem >> 10, i = rem & 1023;
    out[idx] = f2b(W[(size_t)o * (FD * 3) + i * 3 + tau]);
  }
}

// ---------------- zero the pad boundary rows of srcPad ---------------------
__global__ __launch_bounds__(256) void k_zpad(ushort* __restrict__ pad) {
  const int r = blockIdx.x ? TN + 1 : 0;
  const int b = blockIdx.y;
  ushort4 z{0, 0, 0, 0};
  *(ushort4*)(pad + ((size_t)b * (TN + 2) + r) * FD + threadIdx.x * 4) = z;
}

// ---------------- effective bias (z<2) + V-bias copy (z==2) ----------------
__global__ __launch_bounds__(256) void k_beff(const float* __restrict__ in_w,
                                              const float* __restrict__ bq,
                                              const float* __restrict__ bk,
                                              const float* __restrict__ in_b,
                                              float* __restrict__ out) {
  const int n = blockIdx.x, l = blockIdx.y, qk = blockIdx.z;
  const int tid = threadIdx.x;
  if (qk == 2) {
    if (tid == 0)
      out[l * 3 * FD + 2 * FD + n] = in_b[l * 3 * FD + 2 * FD + n];
    return;
  }
  const float* Win = in_w + (size_t)(l * 3 + qk) * FD * FD;
  const float* bv = (qk ? bk : bq) + (size_t)l * FD;
  float s = 0.f;
  for (int j = tid; j < FD; j += 256) s += Win[(size_t)n * FD + j] * bv[j];
  __shared__ float red[4];
#pragma unroll
  for (int o = 32; o; o >>= 1) s += __shfl_xor(s, o);
  if ((tid & 63) == 0) red[tid >> 6] = s;
  __syncthreads();
  if (tid == 0)
    out[l * 3 * FD + qk * FD + n] =
        red[0] + red[1] + red[2] + red[3] + in_b[l * 3 * FD + qk * FD + n];
}

// ---------------- bf16 MFMA GEMM, 128x128 (m97 structure) ------------------
template <bool RELU, bool BF16OUT, bool PREP4 = false>
__global__ __launch_bounds__(256) void k_mm(const ushort* __restrict__ A,
                                            const ushort* __restrict__ W,
                                            const float* __restrict__ bias,
                                            void* __restrict__ Cv,
                                            int M, int N, int K) {
  constexpr size_t FF = (size_t)FD * FD;
  if (PREP4) {
    const int z = blockIdx.z;  // l*2 + qk
    A += (size_t)z * FF;
    W += (size_t)(((z & 1) * 2) + (z >> 1)) * FF;   // qk*2 + l
    Cv = (void*)((ushort*)Cv + (size_t)((z >> 1) * 3 + (z & 1)) * FF);
  }
  __shared__ __align__(16) ushort As[128 * 32];
  __shared__ __align__(16) ushort Ws[128 * 32];
  const int tid = threadIdx.x;
  const int lane = tid & 63, wv = tid >> 6;
  const int l15 = lane & 15, g = lane >> 4;
  const int wr = wv >> 1, wc = wv & 1;
  int bx = blockIdx.x, by = blockIdx.y;
  const int nwg = gridDim.x * gridDim.y;
  if ((nwg & 7) == 0) {  // bijective XCD swizzle (T1)
    int bid = by * gridDim.x + bx;
    bid = (bid & 7) * (nwg >> 3) + (bid >> 3);
    bx = bid % gridDim.x;
    by = bid / gridDim.x;
  }
  const int m0 = by * 128, n0 = bx * 128;
  f32x4 acc[4][4];
#pragma unroll
  for (int i = 0; i < 4; ++i)
#pragma unroll
    for (int j = 0; j < 4; ++j) acc[i][j] = (f32x4){0.f, 0.f, 0.f, 0.f};

  for (int k0 = 0; k0 < K; k0 += 32) {
#pragma unroll
    for (int j = 0; j < 2; ++j) {
      const int u = j * 256 + wv * 64 + lane;
      const int r = u >> 2, c = (u & 3) * 8;
      gld16(A + (size_t)min(m0 + r, M - 1) * K + k0 + c, As + (size_t)u * 8);
    }
#pragma unroll
    for (int j = 0; j < 2; ++j) {
      const int u = j * 256 + wv * 64 + lane;
      const int r = u >> 2, c = (u & 3) * 8;
      gld16(W + (size_t)(n0 + r) * K + k0 + c, Ws + (size_t)u * 8);
    }
    __syncthreads();
    short8 af[4], bfr[4];
#pragma unroll
    for (int i = 0; i < 4; ++i)
      af[i] = *(const short8*)(As + (wr * 64 + i * 16 + l15) * 32 + g * 8);
#pragma unroll
    for (int j = 0; j < 4; ++j)
      bfr[j] = *(const short8*)(Ws + (wc * 64 + j * 16 + l15) * 32 + g * 8);
    __builtin_amdgcn_s_setprio(1);
#pragma unroll
    for (int i = 0; i < 4; ++i)
#pragma unroll
      for (int j = 0; j < 4; ++j)
        acc[i][j] = __builtin_amdgcn_mfma_f32_16x16x32_bf16(af[i], bfr[j],
                                                            acc[i][j], 0, 0, 0);
    __builtin_amdgcn_s_setprio(0);
    __syncthreads();
  }
#pragma unroll
  for (int i = 0; i < 4; ++i) {
#pragma unroll
    for (int r = 0; r < 4; ++r) {
      const int row = m0 + wr * 64 + i * 16 + g * 4 + r;
      if (row >= M) continue;
#pragma unroll
      for (int j = 0; j < 4; ++j) {
        const int col = n0 + wc * 64 + j * 16 + l15;
        float v = acc[i][j][r];
        if (bias) v += bias[col];
        if (RELU) v = fmaxf(v, 0.f);
        if (BF16OUT)
          ((ushort*)Cv)[(size_t)row * N + col] = f2b(v);
        else
          ((float*)Cv)[(size_t)row * N + col] = v;
      }
    }
  }
}

// ---------------- k_mm8: 256x256, BK=32, 3-buffer ring, counted vmcnt ------
__global__ __launch_bounds__(512, 1) void k_mm8(const ushort* __restrict__ A,
                                                const ushort* __restrict__ W,
                                                const float* __restrict__ bias,
                                                ushort* __restrict__ C,
                                                int M, int N, int K) {
  __shared__ __align__(16) ushort As[3][256 * 32];
  __shared__ __align__(16) ushort Bs[3][256 * 32];
  const int tid = threadIdx.x;
  const int lane = tid & 63, wv = tid >> 6;
  const int l15 = lane & 15, g = lane >> 4;
  const int wr = wv >> 2, wc = wv & 3;
  int bx = blockIdx.x, by = blockIdx.y;
  const int nwg = gridDim.x * gridDim.y;
  if ((nwg & 7) == 0) {  // bijective XCD swizzle (T1)
    int bid = by * gridDim.x + bx;
    bid = (bid & 7) * (nwg >> 3) + (bid >> 3);
    bx = bid % gridDim.x;
    by = bid / gridDim.x;
  }
  const int m0 = by * 256, n0 = bx * 256;
  const int NKt = K >> 5;

  f32x4 acc[8][4];
#pragma unroll
  for (int i = 0; i < 8; ++i)
#pragma unroll
    for (int j = 0; j < 4; ++j) acc[i][j] = (f32x4){0.f, 0.f, 0.f, 0.f};

  auto stageA = [&](int kt) {
    ushort* dst = As[kt % 3];
    const int kb = kt * 32;
#pragma unroll
    for (int j = 0; j < 2; ++j) {
      const int u = j * 512 + tid;        // 0..1023
      const int row = u >> 2, s = u & 3;  // row 0..255, 16B slot 0..3
      const int c = s ^ ((row >> 1) & 3);
      gld16(A + (size_t)min(m0 + row, M - 1) * K + kb + c * 8,
            dst + row * 32 + s * 8);
    }
  };
  auto stageB = [&](int kt) {
    ushort* dst = Bs[kt % 3];
    const int kb = kt * 32;
#pragma unroll
    for (int j = 0; j < 2; ++j) {
      const int u = j * 512 + tid;
      const int row = u >> 2, s = u & 3;
      const int c = s ^ ((row >> 1) & 3);
      gld16(W + (size_t)(n0 + row) * K + kb + c * 8, dst + row * 32 + s * 8);
    }
  };

  stageA(0); stageB(0); stageA(1); stageB(1);
  asm volatile("s_waitcnt vmcnt(4)" ::: "memory");
  __builtin_amdgcn_s_barrier();

  for (int t = 0; t < NKt; ++t) {
    const int d = t % 3;
    const ushort* Ab = As[d];
    const ushort* Bb = Bs[d];
    short8 bfr[4];
    {  // phase 0: m-frags 0..3
      short8 afr[4];
#pragma unroll
      for (int mi = 0; mi < 4; ++mi) {
        const int row = wr * 128 + mi * 16 + l15;
        afr[mi] = *(const short8*)(Ab + row * 32 +
                                   ((g ^ ((row >> 1) & 3)) << 3));
      }
#pragma unroll
      for (int ni = 0; ni < 4; ++ni) {
        const int row = wc * 64 + ni * 16 + l15;
        bfr[ni] = *(const short8*)(Bb + row * 32 +
                                   ((g ^ ((row >> 1) & 3)) << 3));
      }
      if (t + 2 < NKt) stageA(t + 2);
      __builtin_amdgcn_s_barrier();
      asm volatile("s_waitcnt lgkmcnt(0)" ::: "memory");
      __builtin_amdgcn_sched_barrier(0);
      __builtin_amdgcn_s_setprio(1);
#pragma unroll
      for (int mi = 0; mi < 4; ++mi)
#pragma unroll
        for (int ni = 0; ni < 4; ++ni)
          acc[mi][ni] = __builtin_amdgcn_mfma_f32_16x16x32_bf16(
              afr[mi], bfr[ni], acc[mi][ni], 0, 0, 0);
      __builtin_amdgcn_s_setprio(0);
      __builtin_amdgcn_s_barrier();
    }
    {  // phase 1: m-frags 4..7
      short8 afr[4];
#pragma unroll
      for (int mi = 0; mi < 4; ++mi) {
        const int row = wr * 128 + (4 + mi) * 16 + l15;
        afr[mi] = *(const short8*)(Ab + row * 32 +
                                   ((g ^ ((row >> 1) & 3)) << 3));
      }
      if (t + 2 < NKt) stageB(t + 2);
      __builtin_amdgcn_s_barrier();
      asm volatile("s_waitcnt lgkmcnt(0)" ::: "memory");
      __builtin_amdgcn_sched_barrier(0);
      __builtin_amdgcn_s_setprio(1);
#pragma unroll
      for (int mi = 0; mi < 4; ++mi)
#pragma unroll
        for (int ni = 0; ni < 4; ++ni)
          acc[4 + mi][ni] = __builtin_amdgcn_mfma_f32_16x16x32_bf16(
              afr[mi], bfr[ni], acc[4 + mi][ni], 0, 0, 0);
      __builtin_amdgcn_s_setprio(0);
      if (t + 1 < NKt) {
        if (t + 2 < NKt)
          asm volatile("s_waitcnt vmcnt(4)" ::: "memory");
        else
          asm volatile("s_waitcnt vmcnt(0)" ::: "memory");
      }
      __builtin_amdgcn_s_barrier();
    }
  }

#pragma unroll
  for (int mi = 0; mi < 8; ++mi) {
#pragma unroll
    for (int r = 0; r < 4; ++r) {
      const int row = m0 + wr * 128 + mi * 16 + g * 4 + r;
      if (row >= M) continue;
#pragma unroll
      for (int ni = 0; ni < 4; ++ni) {
        const int col = n0 + wc * 64 + ni * 16 + l15;
        float v = acc[mi][ni][r];
        if (bias) v += bias[col];
        C[(size_t)row * N + col] = f2b(v);
      }
    }
  }
}

// ---------------- k_mm8b: 256x128, BK=32, 3-ring, vmcnt(3), 72KB LDS -------
// 8 waves = 4M x 2N (64x64/wave). One 16-MFMA phase per k-tile. CONV variant
// uses padded-row A addressing and fp32 NCH relu output.
template <bool CONV>
__global__ __launch_bounds__(512) void k_mm8b(const ushort* __restrict__ A,
                                              const ushort* __restrict__ W,
                                              const float* __restrict__ bias,
                                              void* __restrict__ Cv,
                                              int M, int N, int K) {
  __shared__ __align__(16) ushort As[3][256 * 32];
  __shared__ __align__(16) ushort Bs[3][128 * 32];
  const int tid = threadIdx.x;
  const int lane = tid & 63, wv = tid >> 6;
  const int l15 = lane & 15, g = lane >> 4;
  const int wr = wv >> 1, wc = wv & 1;
  int bx = blockIdx.x, by = blockIdx.y;
  const int nwg = gridDim.x * gridDim.y;
  if ((nwg & 7) == 0) {  // bijective XCD swizzle (T1)
    int bid = by * gridDim.x + bx;
    bid = (bid & 7) * (nwg >> 3) + (bid >> 3);
    bx = bid % gridDim.x;
    by = bid / gridDim.x;
  }
  const int m0 = by * 256, n0 = bx * 128;
  const int NKt = K >> 5;

  f32x4 acc[4][4];
#pragma unroll
  for (int i = 0; i < 4; ++i)
#pragma unroll
    for (int j = 0; j < 4; ++j) acc[i][j] = (f32x4){0.f, 0.f, 0.f, 0.f};

  auto stageA = [&](int kt) {
    ushort* dst = As[kt % 3];
    const int kb = kt * 32;
#pragma unroll
    for (int j = 0; j < 2; ++j) {
      const int u = j * 512 + tid;        // 0..1023
      const int row = u >> 2, s = u & 3;
      const int c = s ^ ((row >> 1) & 3);
      const ushort* ga;
      if (CONV) {
        const int rm = m0 + row;  // M multiple of 256
        const int bb = rm >> 11, tt = rm & 2047;
        ga = A + (size_t)(bb * (TN + 2) + tt + (kb >> 10)) * FD + (kb & 1023) +
             c * 8;
      } else {
        ga = A + (size_t)min(m0 + row, M - 1) * K + kb + c * 8;
      }
      gld16(ga, dst + row * 32 + s * 8);
    }
  };
  auto stageB = [&](int kt) {
    ushort* dst = Bs[kt % 3];
    const int kb = kt * 32;
    const int u = tid;                    // 0..511
    const int row = u >> 2, s = u & 3;    // row 0..127
    const int c = s ^ ((row >> 1) & 3);
    gld16(W + (size_t)(n0 + row) * K + kb + c * 8, dst + row * 32 + s * 8);
  };

  // prologue: tiles 0,1 staged (3 loads each); oldest 3 (tile 0) drained
  stageA(0); stageB(0); stageA(1); stageB(1);
  asm volatile("s_waitcnt vmcnt(3)" ::: "memory");
  __builtin_amdgcn_s_barrier();

  for (int t = 0; t < NKt; ++t) {
    const int d = t % 3;
    const ushort* Ab = As[d];
    const ushort* Bb = Bs[d];
    short8 afr[4], bfr[4];
#pragma unroll
    for (int mi = 0; mi < 4; ++mi) {
      const int row = wr * 64 + mi * 16 + l15;
      afr[mi] = *(const short8*)(Ab + row * 32 + ((g ^ ((row >> 1) & 3)) << 3));
    }
#pragma unroll
    for (int ni = 0; ni < 4; ++ni) {
      const int row = wc * 64 + ni * 16 + l15;
      bfr[ni] = *(const short8*)(Bb + row * 32 + ((g ^ ((row >> 1) & 3)) << 3));
    }
    if (t + 2 < NKt) { stageA(t + 2); stageB(t + 2); }
    __builtin_amdgcn_s_barrier();
    asm volatile("s_waitcnt lgkmcnt(0)" ::: "memory");
    __builtin_amdgcn_sched_barrier(0);
    __builtin_amdgcn_s_setprio(1);
#pragma unroll
    for (int mi = 0; mi < 4; ++mi)
#pragma unroll
      for (int ni = 0; ni < 4; ++ni)
        acc[mi][ni] = __builtin_amdgcn_mfma_f32_16x16x32_bf16(
            afr[mi], bfr[ni], acc[mi][ni], 0, 0, 0);
    __builtin_amdgcn_s_setprio(0);
    if (t + 1 < NKt) {
      if (t + 2 < NKt)
        asm volatile("s_waitcnt vmcnt(3)" ::: "memory");  // t+1 landed
      else
        asm volatile("s_waitcnt vmcnt(0)" ::: "memory");
    }
    __builtin_amdgcn_s_barrier();
  }

#pragma unroll
  for (int mi = 0; mi < 4; ++mi) {
#pragma unroll
    for (int r = 0; r < 4; ++r) {
      const int row = m0 + wr * 64 + mi * 16 + g * 4 + r;
      if (!CONV && row >= M) continue;
#pragma unroll
      for (int ni = 0; ni < 4; ++ni) {
        const int col = n0 + wc * 64 + ni * 16 + l15;
        float v = acc[mi][ni][r];
        if (bias) v += bias[col];
        if (CONV) {
          v = fmaxf(v, 0.f);
          const int bb = row >> 11, tt = row & 2047;
          ((float*)Cv)[((size_t)(bb * FD + col)) * TN + tt] = v;
        } else {
          ((ushort*)Cv)[(size_t)row * N + col] = f2b(v);
        }
      }
    }
  }
}

// ---------------- flash attention: R6-exact + bh-major XCD remap -----------
__global__ __launch_bounds__(256) void k_fattn(const ushort* __restrict__ Qg,
                                               const ushort* __restrict__ Kg,
                                               const ushort* __restrict__ Vt,
                                               ushort* __restrict__ Og) {
  __shared__ __align__(16) ushort Ks[64 * 128];
  __shared__ __align__(16) ushort Vs[128 * 64];
  __shared__ __align__(16) ushort Ps[4][16 * 64];
  const int tid = threadIdx.x, lane = tid & 63, wv = tid >> 6;
  const int l15 = lane & 15, g = lane >> 4;
  const int flat = blockIdx.x + NT * (blockIdx.y + HN * blockIdx.z);
  const int xcd = flat & 7, slot = flat >> 3;   // slot 0..143
  const int grp = xcd + 8 * (slot / NT);        // bh 0..31
  const int qt = slot % NT;
  const int b = grp >> 3, h = grp & 7, q0 = qt * 64;
  const size_t rowBase = (size_t)b * SN;
  const int hoff = h * DH;
  const size_t vbase = (size_t)grp * DH * SN;

  short8 qf[4];
  const int qrow = min(q0 + wv * 16 + l15, SN - 1);
#pragma unroll
  for (int c = 0; c < 4; ++c)
    qf[c] = *(const short8*)(Qg + (rowBase + qrow) * SF + hoff + c * 32 + g * 8);

  short8 onesf;
#pragma unroll
  for (int i = 0; i < 8; ++i) onesf[i] = (short)0x3F80;  // bf16 1.0

  f32x4 o[8];
#pragma unroll
  for (int dt = 0; dt < 8; ++dt) o[dt] = (f32x4){0.f, 0.f, 0.f, 0.f};
  f32x4 lacc = (f32x4){0.f, 0.f, 0.f, 0.f};  // MFMA row-sum of P
  const char* KsB = (const char*)Ks;
  const char* VsB = (const char*)Vs;
  char* PsB = (char*)&Ps[wv][0];

  for (int t = 0; t < NT; ++t) {
    const int kv0 = t * 64;
    const bool tl = (t == NT - 1);
    if (tl) {
#pragma unroll
      for (int j = 0; j < 4; ++j) {
        const int su = j * 256 + tid;
        const int row = su >> 4, s = su & 15;
        const int c16 = s ^ (row & 7);
        const int krow = min(kv0 + row, SN - 1);
        gld16(Kg + (rowBase + krow) * SF + hoff + c16 * 8, Ks + (size_t)su * 8);
      }
#pragma unroll
      for (int j = 0; j < 4; ++j) {
        const int su = j * 256 + tid;
        const int row = su >> 3, s = su & 7;
        const int cc = s ^ (row & 7);
        const int kvc = min(kv0 + cc * 8, SN - 8);
        gld16(Vt + vbase + (size_t)row * SN + kvc, Vs + (size_t)su * 8);
      }
    } else {
#pragma unroll
      for (int j = 0; j < 4; ++j) {
        const int su = j * 256 + tid;
        const int row = su >> 4, s = su & 15;
        const int c16 = s ^ (row & 7);
        gld16(Kg + (rowBase + kv0 + row) * SF + hoff + c16 * 8,
              Ks + (size_t)su * 8);
      }
#pragma unroll
      for (int j = 0; j < 4; ++j) {
        const int su = j * 256 + tid;
        const int row = su >> 3, s = su & 7;
        const int cc = s ^ (row & 7);
        gld16(Vt + vbase + (size_t)row * SN + kv0 + cc * 8,
              Vs + (size_t)su * 8);
      }
    }
    __syncthreads();

    // S^T = K · Q^T
    f32x4 st[4];
    __builtin_amdgcn_s_setprio(1);
#pragma unroll
    for (int kt = 0; kt < 4; ++kt) {
      f32x4 s4 = (f32x4){0.f, 0.f, 0.f, 0.f};
      const int row = kt * 16 + l15;
#pragma unroll
      for (int c = 0; c < 4; ++c) {
        const short8 kf = *(const short8*)(
            KsB + row * 256 + (((c * 4 + g) ^ (row & 7)) << 4));
        s4 = __builtin_amdgcn_mfma_f32_16x16x32_bf16(kf, qf[c], s4, 0, 0, 0);
      }
      st[kt] = s4;
    }
    __builtin_amdgcn_s_setprio(0);

    // no-max softmax: p = 2^(C2*s); mask only on tail tile
    float pfl[16];
    if (tl) {
#pragma unroll
      for (int kt = 0; kt < 4; ++kt)
#pragma unroll
        for (int r = 0; r < 4; ++r) {
          const int kvg = kv0 + kt * 16 + g * 4 + r;
          pfl[kt * 4 + r] = (kvg < SN) ? exp2_fast(C2 * st[kt][r]) : 0.f;
        }
    } else {
#pragma unroll
      for (int i = 0; i < 16; ++i)
        pfl[i] = exp2_fast(C2 * st[i >> 2][i & 3]);
    }

    // write P: row l15, 16B slots XOR-swizzled by (l15&7)
#pragma unroll
    for (int kt = 0; kt < 4; ++kt) {
      const uint lo = cvt_pk_bf16(pfl[kt * 4 + 0], pfl[kt * 4 + 1]);
      const uint hi = cvt_pk_bf16(pfl[kt * 4 + 2], pfl[kt * 4 + 3]);
      const int slot = (kt * 2 + (g >> 1)) ^ (l15 & 7);
      *(uint2*)(PsB + l15 * 128 + slot * 16 + (g & 1) * 8) = make_uint2(lo, hi);
    }

    // PV: O += P · V ; lacc += P · 1 (row-sum via matrix pipe)
    __builtin_amdgcn_s_setprio(1);
#pragma unroll
    for (int c2 = 0; c2 < 2; ++c2) {
      const int pslot = (c2 * 4 + g) ^ (l15 & 7);
      const short8 pf = *(const short8*)(PsB + l15 * 128 + pslot * 16);
      lacc = __builtin_amdgcn_mfma_f32_16x16x32_bf16(pf, onesf, lacc, 0, 0, 0);
#pragma unroll
      for (int dt = 0; dt < 8; ++dt) {
        const int row = dt * 16 + l15;
        const short8 vf = *(const short8*)(
            VsB + row * 128 + (((c2 * 4 + g) ^ (row & 7)) << 4));
        o[dt] = __builtin_amdgcn_mfma_f32_16x16x32_bf16(pf, vf, o[dt], 0, 0, 0);
      }
    }
    __builtin_amdgcn_s_setprio(0);
    __syncthreads();
  }

  float ir[4];
#pragma unroll
  for (int r = 0; r < 4; ++r) ir[r] = 1.f / lacc[r];
#pragma unroll
  for (int r = 0; r < 4; ++r) {
    const int orow = q0 + wv * 16 + g * 4 + r;
    if (orow >= SN) continue;
#pragma unroll
    for (int dt = 0; dt < 8; ++dt)
      Og[(rowBase + orow) * FD + hoff + dt * 16 + l15] = f2b(o[dt][r] * ir[r]);
  }
}

// ---------------- fused residual + LayerNorm (+optional pad write) ---------
template <bool WPAD>
__global__ __launch_bounds__(256) void k_add_ln(ushort* __restrict__ sb,
                                                const ushort* __restrict__ d,
                                                const float* __restrict__ g,
                                                const float* __restrict__ be,
                                                ushort* __restrict__ pad) {
  __shared__ float red[4];
  const int row = blockIdx.x;
  const int tid = threadIdx.x;
  const int c = tid * 4;
  const size_t off = (size_t)row * FD + c;
  const ushort4 sv = *(const ushort4*)(sb + off);
  const ushort4 dv = *(const ushort4*)(d + off);
  float v[4] = {b2f(sv.x) + b2f(dv.x), b2f(sv.y) + b2f(dv.y),
                b2f(sv.z) + b2f(dv.z), b2f(sv.w) + b2f(dv.w)};
  float sum = v[0] + v[1] + v[2] + v[3];
#pragma unroll
  for (int o = 32; o; o >>= 1) sum += __shfl_xor(sum, o);
  if ((tid & 63) == 0) red[tid >> 6] = sum;
  __syncthreads();
  sum = red[0] + red[1] + red[2] + red[3];
  const float mu = sum * (1.f / FD);
  float vs = 0.f;
#pragma unroll
  for (int i = 0; i < 4; ++i) {
    const float t = v[i] - mu;
    vs += t * t;
  }
  __syncthreads();
#pragma unroll
  for (int o = 32; o; o >>= 1) vs += __shfl_xor(vs, o);
  if ((tid & 63) == 0) red[tid >> 6] = vs;
  __syncthreads();
  vs = red[0] + red[1] + red[2] + red[3];
  const float rstd = rsqrtf(vs * (1.f / FD) + 1e-5f);
  const float4 gv = *(const float4*)(g + c);
  const float4 bv = *(const float4*)(be + c);
  ushort4 u{f2b((v[0] - mu) * rstd * gv.x + bv.x),
            f2b((v[1] - mu) * rstd * gv.y + bv.y),
            f2b((v[2] - mu) * rstd * gv.z + bv.z),
            f2b((v[3] - mu) * rstd * gv.w + bv.w)};
  *(ushort4*)(sb + off) = u;
  if (WPAD) {
    const int b = row / SN, s = row % SN;
    if (s < TN)
      *(ushort4*)(pad + ((size_t)(b * (TN + 2) + s + 1)) * FD + c) = u;
  }
}

// ---------------------------------------------------------------------------
extern "C" void kernel_launch(void* const* d_in, const int* in_sizes, int n_in,
                              void* d_out, int out_size, void* d_ws,
                              size_t ws_size, hipStream_t stream) {
  const float* x      = (const float*)d_in[0];
  const float* proto  = (const float*)d_in[1];
  const float* wq     = (const float*)d_in[2];
  const float* bq     = (const float*)d_in[3];
  const float* wk     = (const float*)d_in[4];
  const float* bk     = (const float*)d_in[5];
  const float* in_w   = (const float*)d_in[6];
  const float* in_b   = (const float*)d_in[7];
  const float* out_w  = (const float*)d_in[8];
  const float* out_b  = (const float*)d_in[9];
  const float* l1_w   = (const float*)d_in[10];
  const float* l1_b   = (const float*)d_in[11];
  const float* l2_w   = (const float*)d_in[12];
  const float* l2_b   = (const float*)d_in[13];
  const float* ln1_g  = (const float*)d_in[14];
  const float* ln1_b  = (const float*)d_in[15];
  const float* ln2_g  = (const float*)d_in[16];
  const float* ln2_b  = (const float*)d_in[17];
  const float* emb_w  = (const float*)d_in[18];
  const float* emb_b  = (const float*)d_in[19];

  char* p = (char*)d_ws;
  auto take = [&](size_t bytes) {
    char* r = p;
    p += (bytes + 255) & ~(size_t)255;
    return r;
  };
  const size_t MF = (size_t)MR * FD;
  const size_t FF = (size_t)FD * FD;
  ushort* srcb   = (ushort*)take(MF * 2);
  ushort* bQKV   = (ushort*)take((size_t)MR * SF * 2);  // 55 MB, multi-aliased
  ushort* bVt    = (ushort*)take((size_t)BN * HN * DH * SN * 2);
  ushort* bO     = (ushort*)take(MF * 2);
  ushort* bFF    = (ushort*)take((size_t)MR * DF * 2);
  ushort* wQKV   = (ushort*)take((size_t)2 * 3 * FF * 2);  // packed weights
  ushort* wOut   = (ushort*)take((size_t)2 * FF * 2);
  ushort* wL1    = (ushort*)take((size_t)2 * DF * FD * 2);
  ushort* wL2    = (ushort*)take((size_t)2 * FD * DF * 2);
  float*  bqkv   = (float*)take((size_t)2 * SF * 4);
  ushort* srcPad = (ushort*)take((size_t)BN * (TN + 2) * FD * 2);  // dedicated
  ushort* convW  = (ushort*)take((size_t)3 * FF * 2);              // dedicated
  // aliases inside bQKV (lifetimes disjoint from activation use):
  ushort* wT    = bQKV;             // prep: 4 * F*F bf16
  ushort* wInQK = bQKV + 4 * FF;    // prep: 4 * F*F bf16
  ushort* bOut  = bQKV;             // post-attn / post-FFN2 bf16

  // ---- prep (all weight-only work hoisted, consolidated) ----
  k_build<<<MR, 256, 0, stream>>>(x, proto, srcb);
  k_cvt_inw<<<2048, 256, 0, stream>>>(in_w, wInQK, wQKV);
  k_cvt<<<1024, 256, 0, stream>>>(out_w, wOut, 2 * FF);
  k_cvt<<<256, 256, 0, stream>>>(l1_w, wL1, 2 * DF * FD);
  k_cvt<<<256, 256, 0, stream>>>(l2_w, wL2, 2 * FD * DF);
  k_cvtT<<<dim3(32, 32, 4), 256, 0, stream>>>(wq, wk, wT);
  k_mm<false, true, true><<<dim3(8, 8, 4), 256, 0, stream>>>(
      wInQK, wT, nullptr, wQKV, FD, FD, FD);
  k_beff<<<dim3(FD, 2, 3), 256, 0, stream>>>(in_w, bq, bk, in_b, bqkv);
  k_convw<<<1024, 256, 0, stream>>>(emb_w, convW);
  k_zpad<<<dim3(2, BN), 256, 0, stream>>>(srcPad);

  const int MB = (MR + 127) / 128;    // 71 (128-tiles)
  const int MB2 = (MR + 255) / 256;   // 36 (256-tiles)

  // ---- layers ----
  for (int l = 0; l < 2; ++l) {
    k_mm8<<<dim3(SF / 256, MB2), 512, 0, stream>>>(
        srcb, wQKV + (size_t)l * 3 * FF, bqkv + (size_t)l * SF, bQKV, MR, SF,
        FD);
    k_vT<<<dim3((SN + 31) / 32, DH / 32, BN * HN), 256, 0, stream>>>(
        bQKV + 2 * FD, bVt);
    k_fattn<<<dim3(NT, HN, BN), 256, 0, stream>>>(bQKV, bQKV + FD, bVt, bO);
    k_mm8b<false><<<dim3(FD / 128, MB2), 512, 0, stream>>>(
        bO, wOut + (size_t)l * FF, out_b + (size_t)l * FD, bOut, MR, FD, FD);
    k_add_ln<false><<<MR, 256, 0, stream>>>(srcb, bOut,
                                            ln1_g + (size_t)l * FD,
                                            ln1_b + (size_t)l * FD, nullptr);
    k_mm<true, true><<<dim3(DF / 128, MB), 256, 0, stream>>>(
        srcb, wL1 + (size_t)l * DF * FD, l1_b + (size_t)l * DF, bFF, MR, DF,
        FD);
    k_mm<false, true><<<dim3(FD / 128, MB), 256, 0, stream>>>(
        bFF, wL2 + (size_t)l * FD * DF, l2_b + (size_t)l * FD, bOut, MR, FD,
        DF);
    if (l == 1)
      k_add_ln<true><<<MR, 256, 0, stream>>>(srcb, bOut,
                                             ln2_g + (size_t)l * FD,
                                             ln2_b + (size_t)l * FD, srcPad);
    else
      k_add_ln<false><<<MR, 256, 0, stream>>>(srcb, bOut,
                                              ln2_g + (size_t)l * FD,
                                              ln2_b + (size_t)l * FD, nullptr);
  }

  // ---- conv head ----
  k_mm8b<true><<<dim3(FD / 128, (BN * TN) / 256), 512, 0, stream>>>(
      srcPad, convW, emb_b, (float*)d_out, BN * TN, FD, 3 * FD);
}